// Round 4
// baseline (644.940 us; speedup 1.0000x reference)
//
#include <hip/hip_runtime.h>
#include <math.h>

#define N_ANCHN 18675
#define NPAD    18688
#define BATCH   16
#define PRE     12000
#define CPAD    12032
#define WPB     188      // CPAD/64 words per row
#define POST    2000
#define NMS_T   0.7f
#define IMGX    1333.0f
#define IMGY    402.0f
#define MINSZ   16.0f
#define NBUCK   256
#define KINV    0x007FFFFFu   // key_of(-inf)
#define MLCAP   12288

typedef unsigned long long u64;

__device__ __forceinline__ unsigned key_of(float f) {
  unsigned u = __float_as_uint(f);
  return (u & 0x80000000u) ? ~u : (u | 0x80000000u);
}

// Reference-exact IoU: inter/(a_area + b_area - inter), +1 box convention, no FMA.
__device__ __forceinline__ float iou_ref(float ax1, float ay1, float ax2, float ay2, float aar,
                                         float bx1, float by1, float bx2, float by2, float bar) {
  float xx1 = fmaxf(ax1, bx1);
  float yy1 = fmaxf(ay1, by1);
  float xx2 = fminf(ax2, bx2);
  float yy2 = fminf(ay2, by2);
  float iw = fmaxf(0.0f, __fadd_rn(__fsub_rn(xx2, xx1), 1.0f));
  float ih = fmaxf(0.0f, __fadd_rn(__fsub_rn(yy2, yy1), 1.0f));
  float inter = __fmul_rn(iw, ih);
  return __fdiv_rn(inter, __fsub_rn(__fadd_rn(aar, bar), inter));
}

// Decision-identical to (iou_ref > 0.7): band bounds 0.395/0.43 vs exact 0.41176
// leave ~4% slack against <=1e-6 float rounding; middle band recomputes ref-exact.
__device__ __forceinline__ bool hit_test(float ix1, float iy1, float ix2, float iy2, float iar,
                                         float jx1, float jy1, float jx2, float jy2, float jar) {
  float xx1 = fmaxf(ix1, jx1);
  float yy1 = fmaxf(iy1, jy1);
  float xx2 = fminf(ix2, jx2);
  float yy2 = fminf(iy2, jy2);
  float iw = fmaxf(0.0f, __fadd_rn(__fsub_rn(xx2, xx1), 1.0f));
  float ih = fmaxf(0.0f, __fadd_rn(__fsub_rn(yy2, yy1), 1.0f));
  float inter = __fmul_rn(iw, ih);
  float S = __fadd_rn(iar, jar);
  if (inter >= __fmul_rn(0.43f, S)) return true;
  if (inter <= __fmul_rn(0.395f, S)) return false;
  return __fdiv_rn(inter, __fsub_rn(S, inter)) > NMS_T;
}

__device__ __forceinline__ void emit_hit(int lo, int hi, u64* diagb, unsigned* rcb,
                                         unsigned short* rtb, int L) {
  if ((hi >> 6) == (lo >> 6)) {
    atomicOr(&diagb[(size_t)(lo >> 6) * 64 + (hi & 63)], 1ull << (lo & 63));
  } else {
    unsigned slot = atomicAdd(&rcb[lo], 1u);
    if ((int)slot < L) rtb[(size_t)lo * L + slot] = (unsigned short)hi;
  }
}

__device__ __forceinline__ void decode_one(
    const float* __restrict__ anchors, const float* __restrict__ cls,
    const float* __restrict__ bbox, int b, int i,
    float& x1, float& y1, float& x2, float& y2, unsigned& key) {
  float4 A = *(const float4*)(anchors + (size_t)i * 4);
  float ah = __fsub_rn(A.w, A.y);
  float aw = __fsub_rn(A.z, A.x);
  float acy = __fadd_rn(A.y, __fmul_rn(0.5f, ah));
  float acx = __fadd_rn(A.x, __fmul_rn(0.5f, aw));

  float4 P = *(const float4*)(bbox + ((size_t)b * N_ANCHN + i) * 4);
  float dx = P.x, dy = P.y, dw = P.z, dh = P.w;

  float cy = __fadd_rn(__fmul_rn(dy, ah), acy);
  float cx = __fadd_rn(__fmul_rn(dx, aw), acx);
  float eh = (float)exp((double)dh);
  float ew = (float)exp((double)dw);
  float h = __fmul_rn(eh, ah);
  float w = __fmul_rn(ew, aw);

  x1 = fminf(fmaxf(__fsub_rn(cx, __fmul_rn(0.5f, w)), 0.0f), IMGX);
  y1 = fminf(fmaxf(__fsub_rn(cy, __fmul_rn(0.5f, h)), 0.0f), IMGY);
  x2 = fminf(fmaxf(__fadd_rn(cx, __fmul_rn(0.5f, w)), 0.0f), IMGX);
  y2 = fminf(fmaxf(__fadd_rn(cy, __fmul_rn(0.5f, h)), 0.0f), IMGY);

  bool valid = (__fsub_rn(y2, y1) >= MINSZ) && (__fsub_rn(x2, x1) >= MINSZ);
  float s = valid ? cls[(size_t)b * (2 * N_ANCHN) + 2 * i + 1] : -INFINITY;
  key = key_of(s);
}

// ---------------- Kernel 1: full-grid decode (+ zeroing column) ----------------
__global__ __launch_bounds__(256) void decode_kernel(
    const float* __restrict__ anchors, const float* __restrict__ cls,
    const float* __restrict__ bbox,
    float* __restrict__ bx1, float* __restrict__ by1,
    float* __restrict__ bx2, float* __restrict__ by2,
    unsigned* __restrict__ keys,
    u64* __restrict__ diag, unsigned* __restrict__ rowcnt) {
  const int bx = blockIdx.x;
  const int b = blockIdx.y;
  if (bx == gridDim.x - 1) {
    u64* dz = diag + (size_t)b * WPB * 64;
    for (int i = threadIdx.x; i < WPB * 64; i += 256) dz[i] = 0ull;
    unsigned* rz = rowcnt + (size_t)b * CPAD;
    for (int i = threadIdx.x; i < CPAD; i += 256) rz[i] = 0u;
    return;
  }
  int i = bx * 256 + threadIdx.x;
  if (i >= N_ANCHN) return;
  float x1, y1, x2, y2; unsigned k;
  decode_one(anchors, cls, bbox, b, i, x1, y1, x2, y2, k);
  size_t o = (size_t)b * NPAD + i;
  bx1[o] = x1; by1[o] = y1; bx2[o] = x2; by2[o] = y2;
  keys[o] = k;
}

// ---------------- Kernel 2: prep (radix-select + compaction) + x-sort ----------------
__global__ __launch_bounds__(1024) void prepsort_kernel(
    const unsigned* __restrict__ keys,
    const float* __restrict__ bx1, const float* __restrict__ by1,
    const float* __restrict__ bx2, const float* __restrict__ by2,
    float* __restrict__ cx1, float* __restrict__ cy1,
    float* __restrict__ cx2, float* __restrict__ cy2,
    float* __restrict__ car, int* __restrict__ ncand,
    float* __restrict__ sx1, float* __restrict__ sy1,
    float* __restrict__ sx2, float* __restrict__ sy2,
    float* __restrict__ sar, int* __restrict__ sperm,
    float* __restrict__ wminx1, float* __restrict__ wmaxx2) {
  const int b = blockIdx.x;
  const int tid = threadIdx.x;
  const int lane = tid & 63;
  const int wv = tid >> 6;
  __shared__ unsigned hist[16][256];
  __shared__ unsigned mh[256];
  __shared__ unsigned wsum[16];
  __shared__ unsigned bh[NBUCK];
  __shared__ unsigned boff[NBUCK];
  __shared__ unsigned char fb[NPAD];
  __shared__ unsigned short mlist[MLCAP];
  __shared__ unsigned sh_prefix, sh_k, sh_n, sh_mcount;
  const unsigned* kb = keys + (size_t)b * NPAD;

  if (tid == 0) { sh_prefix = 0u; sh_k = PRE; sh_mcount = 0u; }
  __syncthreads();

  // ---- radix level 0 (full scan) ----
  {
    for (int idx = tid; idx < 16 * 256; idx += 1024) ((unsigned*)hist)[idx] = 0u;
    __syncthreads();
    for (int i = tid; i < N_ANCHN; i += 1024)
      atomicAdd(&hist[wv][kb[i] >> 24], 1u);
    __syncthreads();
    if (tid < 256) {
      unsigned s = 0;
#pragma unroll
      for (int q = 0; q < 16; ++q) s += hist[q][tid];
      mh[tid] = s;
    }
    __syncthreads();
    if (tid == 0) {
      unsigned kk = sh_k, cum = 0;
      for (int d = 255; d >= 0; --d) {
        unsigned c = mh[d];
        if (cum + c >= kk) { sh_k = kk - cum; sh_prefix = (unsigned)d << 24; break; }
        cum += c;
      }
    }
    __syncthreads();
  }

  // ---- compact indices matching top byte (narrows levels 1-3) ----
  {
    unsigned b0 = sh_prefix >> 24;
    for (int i = tid; i < N_ANCHN; i += 1024) {
      if ((kb[i] >> 24) == b0) {
        unsigned p = atomicAdd(&sh_mcount, 1u);
        if (p < MLCAP) mlist[p] = (unsigned short)i;
      }
    }
  }
  __syncthreads();
  const bool useList = (sh_mcount <= (unsigned)MLCAP);
  const unsigned mcount = min(sh_mcount, (unsigned)MLCAP);

  // ---- radix levels 1-3 (list-narrowed; exact fallback) ----
  for (int level = 1; level < 4; ++level) {
    const int shift = 24 - 8 * level;
    for (int idx = tid; idx < 16 * 256; idx += 1024) ((unsigned*)hist)[idx] = 0u;
    __syncthreads();
    unsigned pre = sh_prefix;
    if (useList) {
      for (int idx = tid; idx < (int)mcount; idx += 1024) {
        unsigned k = kb[mlist[idx]];
        if ((k >> (shift + 8)) == (pre >> (shift + 8)))
          atomicAdd(&hist[wv][(k >> shift) & 255u], 1u);
      }
    } else {
      for (int i = tid; i < N_ANCHN; i += 1024) {
        unsigned k = kb[i];
        if ((k >> (shift + 8)) == (pre >> (shift + 8)))
          atomicAdd(&hist[wv][(k >> shift) & 255u], 1u);
      }
    }
    __syncthreads();
    if (tid < 256) {
      unsigned s = 0;
#pragma unroll
      for (int q = 0; q < 16; ++q) s += hist[q][tid];
      mh[tid] = s;
    }
    __syncthreads();
    if (tid == 0) {
      unsigned kk = sh_k, cum = 0;
      for (int d = 255; d >= 0; --d) {
        unsigned c = mh[d];
        if (cum + c >= kk) { sh_k = kk - cum; sh_prefix = pre | ((unsigned)d << shift); break; }
        cum += c;
      }
    }
    __syncthreads();
  }
  const unsigned T = sh_prefix;
  // radix-select invariant: after the last level, sh_k = PRE - count(keys > T) = tie slots
  const unsigned slots = sh_k;

  const int SEG = (N_ANCHN + 1023) / 1024;

  // ---- flags with stable tie-rank (keys only; wave-scan for tie prefix) ----
  {
    int i0 = tid * SEG, i1 = min(N_ANCHN, i0 + SEG);
    unsigned cnt = 0;
    for (int i = i0; i < i1; ++i) cnt += (kb[i] == T) ? 1u : 0u;
    unsigned v = cnt;
#pragma unroll
    for (int d = 1; d < 64; d <<= 1) {
      unsigned y = __shfl_up(v, d, 64);
      if (lane >= d) v += y;
    }
    if (lane == 63) wsum[wv] = v;
    __syncthreads();
    if (tid == 0) {
      unsigned acc = 0;
#pragma unroll
      for (int q = 0; q < 16; ++q) { unsigned t = wsum[q]; wsum[q] = acc; acc += t; }
    }
    __syncthreads();
    unsigned r = wsum[wv] + v - cnt;   // exclusive tie rank base
    for (int i = i0; i < i1; ++i) {
      unsigned k = kb[i];
      bool tie = (k == T);
      bool cand = (k > T) || (tie && T > KINV && r < slots);
      if (tie) r++;
      fb[i] = cand ? (unsigned char)1 : (unsigned char)0;
    }
  }
  __syncthreads();

  // ---- ordered compaction: descending anchor index (wave-scan prefix) ----
  const float* X1 = bx1 + (size_t)b * NPAD;
  const float* Y1 = by1 + (size_t)b * NPAD;
  const float* X2 = bx2 + (size_t)b * NPAD;
  const float* Y2 = by2 + (size_t)b * NPAD;
  {
    int j0 = tid * SEG, j1 = min(N_ANCHN, j0 + SEG);
    unsigned cnt = 0;
    for (int j = j0; j < j1; ++j) cnt += fb[N_ANCHN - 1 - j];
    unsigned v = cnt;
#pragma unroll
    for (int d = 1; d < 64; d <<= 1) {
      unsigned y = __shfl_up(v, d, 64);
      if (lane >= d) v += y;
    }
    if (lane == 63) wsum[wv] = v;
    __syncthreads();
    if (tid == 0) {
      unsigned acc = 0;
#pragma unroll
      for (int q = 0; q < 16; ++q) { unsigned t = wsum[q]; wsum[q] = acc; acc += t; }
      sh_n = acc;
    }
    __syncthreads();
    unsigned p = wsum[wv] + v - cnt;
    if (tid == 0) ncand[b] = (int)sh_n;
    float* CX1 = cx1 + (size_t)b * CPAD;
    float* CY1 = cy1 + (size_t)b * CPAD;
    float* CX2 = cx2 + (size_t)b * CPAD;
    float* CY2 = cy2 + (size_t)b * CPAD;
    float* CAR = car + (size_t)b * CPAD;
    for (int j = j0; j < j1; ++j) {
      int i = N_ANCHN - 1 - j;
      if (fb[i]) {
        float x1v = X1[i], y1v = Y1[i], x2v = X2[i], y2v = Y2[i];
        CX1[p] = x1v; CY1[p] = y1v; CX2[p] = x2v; CY2[p] = y2v;
        CAR[p] = __fmul_rn(__fadd_rn(__fsub_rn(x2v, x1v), 1.0f),
                           __fadd_rn(__fsub_rn(y2v, y1v), 1.0f));
        p++;
      }
    }
  }
  __syncthreads();
  const int n = (int)sh_n;

  // ---- 256-bucket x1 sort + per-word aggregates (R7-proven layout) ----
  const float scale = (float)NBUCK / 1334.0f;
  const float* CX1 = cx1 + (size_t)b * CPAD;
  const float* CY1 = cy1 + (size_t)b * CPAD;
  const float* CX2 = cx2 + (size_t)b * CPAD;
  const float* CY2 = cy2 + (size_t)b * CPAD;
  const float* CAR = car + (size_t)b * CPAD;
  float* SX1 = sx1 + (size_t)b * CPAD;
  float* SY1 = sy1 + (size_t)b * CPAD;
  float* SX2 = sx2 + (size_t)b * CPAD;
  float* SY2 = sy2 + (size_t)b * CPAD;
  float* SAR = sar + (size_t)b * CPAD;
  int* SP = sperm + (size_t)b * CPAD;

  if (tid < NBUCK) bh[tid] = 0u;
  __syncthreads();
  for (int i = tid; i < n; i += 1024) {
    int q = (int)(CX1[i] * scale);
    q = q < 0 ? 0 : (q > NBUCK - 1 ? NBUCK - 1 : q);
    atomicAdd(&bh[q], 1u);
  }
  __syncthreads();
  if (tid < 64) {
    unsigned carry = 0;
    for (int c = 0; c < 4; ++c) {
      unsigned own = bh[c * 64 + tid];
      unsigned v = own;
      for (int d = 1; d < 64; d <<= 1) {
        unsigned y = __shfl_up(v, d, 64);
        if (tid >= d) v += y;
      }
      boff[c * 64 + tid] = carry + v - own;
      carry += __shfl(v, 63, 64);
    }
  }
  __syncthreads();
  for (int i = tid; i < n; i += 1024) {
    float x1v = CX1[i];
    int q = (int)(x1v * scale);
    q = q < 0 ? 0 : (q > NBUCK - 1 ? NBUCK - 1 : q);
    unsigned p = atomicAdd(&boff[q], 1u);
    SX1[p] = x1v; SY1[p] = CY1[i]; SX2[p] = CX2[i]; SY2[p] = CY2[i];
    SAR[p] = CAR[i]; SP[p] = i;
  }
  for (int i = n + tid; i < CPAD; i += 1024) {
    SX1[i] = 1e30f; SY1[i] = 1e30f; SX2[i] = -1e30f; SY2[i] = -1e30f;
    SAR[i] = 1.0f; SP[i] = 0;
  }
  __syncthreads();
  // wave-parallel per-word aggregates: wave wv handles words wv, wv+16, ...
  for (int w = wv; w < WPB; w += 16) {
    float mn = SX1[64 * w + lane];
    float mx = SX2[64 * w + lane];
#pragma unroll
    for (int d = 32; d > 0; d >>= 1) {
      mn = fminf(mn, __shfl_xor(mn, d, 64));
      mx = fmaxf(mx, __shfl_xor(mx, d, 64));
    }
    if (lane == 0) {
      wminx1[(size_t)b * WPB + w] = mn;
      wmaxx2[(size_t)b * WPB + w] = mx;
    }
  }
}

// ---------------- Kernel 3: transposed banded build, 1-wave blocks, 4 words/wave ----------------
// Block = 1 wave = (row word R, column group G of 4 words). Each lane holds 4
// columns (words 4G..4G+3) in registers; the loop iterates R's rows (wave-
// uniform broadcast from LDS, 2 reads/row feeding 4 hit_tests), with the NEXT
// row's broadcasts prefetched before the current row's tests execute so the
// ~120-cyc LDS latency hides under the VALU work. Per-(row,word) band test
// rx2+2 >= WMN[w] and dedup (w>R | lane>k) are unchanged from the proven R2
// kernel -> identical hit set.
__global__ __launch_bounds__(64) void build_kernel(
    const float* __restrict__ sx1, const float* __restrict__ sy1,
    const float* __restrict__ sx2, const float* __restrict__ sy2,
    const float* __restrict__ sar, const int* __restrict__ sperm,
    const int* __restrict__ ncand,
    const float* __restrict__ wminx1, const float* __restrict__ wmaxx2,
    u64* __restrict__ diagT, unsigned* __restrict__ rowcnt,
    unsigned short* __restrict__ rows_t, int L) {
  const int R = blockIdx.x, G = blockIdx.y, b = blockIdx.z;
  const int n = ncand[b];
  if (64 * R >= n) return;
  if (4 * G + 3 < R) return;        // whole group below row word -> dedup always false
  const float* WMN = wminx1 + (size_t)b * WPB;
  const float rlim = __fadd_rn(wmaxx2[(size_t)b * WPB + R], 2.0f);

  const int w0 = 4 * G;
  const float wmn0 = WMN[w0], wmn1 = WMN[w0 + 1], wmn2 = WMN[w0 + 2], wmn3 = WMN[w0 + 3];
  // pad words have wmn=1e30 > rlim -> auto-invalid
  const bool v0 = (w0     >= R) && (wmn0 <= rlim);
  const bool v1 = (w0 + 1 >= R) && (wmn1 <= rlim);
  const bool v2 = (w0 + 2 >= R) && (wmn2 <= rlim);
  const bool v3 = (w0 + 3 >= R) && (wmn3 <= rlim);
  if (!(v0 | v1 | v2 | v3)) return;

  const float* SX1 = sx1 + (size_t)b * CPAD;
  const float* SY1 = sy1 + (size_t)b * CPAD;
  const float* SX2 = sx2 + (size_t)b * CPAD;
  const float* SY2 = sy2 + (size_t)b * CPAD;
  const float* SAR = sar + (size_t)b * CPAD;
  const int* SP = sperm + (size_t)b * CPAD;

  const int lane = threadIdx.x;

  // stage the 64 rows of word R: box (float4) + packed {area, sperm} (float2)
  __shared__ float4 rbv[64];
  __shared__ float2 ras[64];
  float rx2own;
  {
    int i = 64 * R + lane;
    float4 v = make_float4(SX1[i], SY1[i], SX2[i], SY2[i]);
    rbv[lane] = v;
    ras[lane] = make_float2(SAR[i], __int_as_float(SP[i]));
    rx2own = v.z;
  }

  // this wave's 4 columns per lane, in registers (loads skipped for invalid words)
  float c0x1 = 1e30f, c0y1 = 0.f, c0x2 = 0.f, c0y2 = 0.f, c0ar = 1.f; int c0sp = 0;
  float c1x1 = 1e30f, c1y1 = 0.f, c1x2 = 0.f, c1y2 = 0.f, c1ar = 1.f; int c1sp = 0;
  float c2x1 = 1e30f, c2y1 = 0.f, c2x2 = 0.f, c2y2 = 0.f, c2ar = 1.f; int c2sp = 0;
  float c3x1 = 1e30f, c3y1 = 0.f, c3x2 = 0.f, c3y2 = 0.f, c3ar = 1.f; int c3sp = 0;
  if (v0) { int j = 64 * w0 + lane;
    c0x1 = SX1[j]; c0y1 = SY1[j]; c0x2 = SX2[j]; c0y2 = SY2[j]; c0ar = SAR[j]; c0sp = SP[j]; }
  if (v1) { int j = 64 * (w0 + 1) + lane;
    c1x1 = SX1[j]; c1y1 = SY1[j]; c1x2 = SX2[j]; c1y2 = SY2[j]; c1ar = SAR[j]; c1sp = SP[j]; }
  if (v2) { int j = 64 * (w0 + 2) + lane;
    c2x1 = SX1[j]; c2y1 = SY1[j]; c2x2 = SX2[j]; c2y2 = SY2[j]; c2ar = SAR[j]; c2sp = SP[j]; }
  if (v3) { int j = 64 * (w0 + 3) + lane;
    c3x1 = SX1[j]; c3y1 = SY1[j]; c3x2 = SX2[j]; c3y2 = SY2[j]; c3ar = SAR[j]; c3sp = SP[j]; }
  __syncthreads();   // orders LDS writes before dynamic-index reads (1-wave: ~free)

  // active-row mask from the loosest (lowest-wmn) valid word
  const float wmnlo = v0 ? wmn0 : (v1 ? wmn1 : (v2 ? wmn2 : wmn3));
  u64 a = __ballot(rx2own >= __fsub_rn(wmnlo, 2.0f));
  if (!a) return;

  const float wmn0m2 = __fsub_rn(wmn0, 2.0f);
  const float wmn1m2 = __fsub_rn(wmn1, 2.0f);
  const float wmn2m2 = __fsub_rn(wmn2, 2.0f);
  const float wmn3m2 = __fsub_rn(wmn3, 2.0f);
  const bool g0 = (w0 > R),     e0 = (w0 == R);
  const bool g1 = (w0 + 1 > R), e1 = (w0 + 1 == R);
  const bool g2 = (w0 + 2 > R), e2 = (w0 + 2 == R);
  const bool g3 = (w0 + 3 > R), e3 = (w0 + 3 == R);

  u64* diagb = diagT + (size_t)b * WPB * 64;
  unsigned* rcb = rowcnt + (size_t)b * CPAD;
  unsigned short* rtb = rows_t + (size_t)b * L * CPAD;

  int k = (int)__builtin_ctzll(a);
  float4 RB = rbv[k];
  float2 AS = ras[k];
  while (true) {
    a &= a - 1;
    const int kn = a ? (int)__builtin_ctzll(a) : 0;
    const float4 RBn = rbv[kn];      // prefetch next row (dummy k=0 when done)
    const float2 ASn = ras[kn];
    const float rx2k = RB.z;
    const float rark = AS.x;
    const int rsp = __float_as_int(AS.y);
    if (v0 && rx2k >= wmn0m2) {
      bool dd = g0 | (e0 & (lane > k));
      if (dd && hit_test(RB.x, RB.y, RB.z, RB.w, rark, c0x1, c0y1, c0x2, c0y2, c0ar)) {
        int lo = min(rsp, c0sp), hi = max(rsp, c0sp);
        emit_hit(lo, hi, diagb, rcb, rtb, L);
      }
    }
    if (v1 && rx2k >= wmn1m2) {
      bool dd = g1 | (e1 & (lane > k));
      if (dd && hit_test(RB.x, RB.y, RB.z, RB.w, rark, c1x1, c1y1, c1x2, c1y2, c1ar)) {
        int lo = min(rsp, c1sp), hi = max(rsp, c1sp);
        emit_hit(lo, hi, diagb, rcb, rtb, L);
      }
    }
    if (v2 && rx2k >= wmn2m2) {
      bool dd = g2 | (e2 & (lane > k));
      if (dd && hit_test(RB.x, RB.y, RB.z, RB.w, rark, c2x1, c2y1, c2x2, c2y2, c2ar)) {
        int lo = min(rsp, c2sp), hi = max(rsp, c2sp);
        emit_hit(lo, hi, diagb, rcb, rtb, L);
      }
    }
    if (v3 && rx2k >= wmn3m2) {
      bool dd = g3 | (e3 & (lane > k));
      if (dd && hit_test(RB.x, RB.y, RB.z, RB.w, rark, c3x1, c3y1, c3x2, c3y2, c3ar)) {
        int lo = min(rsp, c3sp), hi = max(rsp, c3sp);
        emit_hit(lo, hi, diagb, rcb, rtb, L);
      }
    }
    if (!a) break;
    k = kn; RB = RBn; AS = ASn;
  }
}

// ---------------- Kernel 4: ballot-chain greedy NMS, 4-deep group prefetch ----------------
// R4: (a) entries 16..31 of a selected box's suppression list are applied via
// two uint4 loads + unrolled LDS atomics (was: serial per-2B global loads with
// exposed latency); (b) the cw>L overflow rescan is WAVE-COOPERATIVE: overflow-
// selected lanes are balloted, then all 64 lanes stride the column range
// together (was: ONE lane serially scanning up to ~12000 columns — the big
// latency tail). Suppression is an idempotent atomicOr into LDS supp, so the
// hit set and selection order are bit-identical.
#define DECLW(s) u64 kw##s; unsigned cw##s; uint4 p0##s, p1##s;
#define LOADW(s, wexp) { int w_ = (wexp); int c_ = 64 * w_ + lane; \
  kw##s = diagb[(size_t)w_ * 64 + lane]; cw##s = rcb[c_]; \
  const uint4* rp_ = (const uint4*)(rtb + (size_t)c_ * L); p0##s = rp_[0]; p1##s = rp_[1]; }
#define PROCW(s, wexp) { int w_ = (wexp); \
  if (w_ < nw && sc < POST) { \
    const int base_ = 64 * w_; const int myc_ = base_ + lane; \
    bool al = (myc_ < n) && !((supp[2 * w_ + (lane >> 5)] >> (lane & 31)) & 1u); \
    u64 act = __ballot(al); bool selme = false; \
    while (act && sc < POST) { \
      int j = (int)__builtin_ctzll(act); \
      if (lane == 0) sel[sc] = base_ + j; \
      sc++; selme |= (lane == j); \
      if ((kw##s >> j) & 1ull) al = false; \
      u64 gt = (j < 63) ? (~0ull << (j + 1)) : 0ull; \
      act = __ballot(al) & gt; } \
    if (selme) { \
      const int ce_ = min((int)cw##s, L); \
      uint4 p2_ = {0,0,0,0}, p3_ = {0,0,0,0}; \
      if (ce_ > 16) { \
        const uint4* rp_ = (const uint4*)(rtb + (size_t)myc_ * L); \
        p2_ = rp_[2]; p3_ = rp_[3]; \
      } \
      unsigned ev_[8] = {p0##s.x, p0##s.y, p0##s.z, p0##s.w, p1##s.x, p1##s.y, p1##s.z, p1##s.w}; \
      _Pragma("unroll") \
      for (int u_ = 0; u_ < 8; ++u_) { \
        if (2 * u_ < ce_)     { int t_ = (int)(ev_[u_] & 0xffffu); atomicOr(&supp[t_ >> 5], 1u << (t_ & 31)); } \
        if (2 * u_ + 1 < ce_) { int t_ = (int)(ev_[u_] >> 16);     atomicOr(&supp[t_ >> 5], 1u << (t_ & 31)); } } \
      if (ce_ > 16) { \
        unsigned e2_[8] = {p2_.x, p2_.y, p2_.z, p2_.w, p3_.x, p3_.y, p3_.z, p3_.w}; \
        _Pragma("unroll") \
        for (int u_ = 0; u_ < 8; ++u_) { \
          if (16 + 2 * u_ < ce_)     { int t_ = (int)(e2_[u_] & 0xffffu); atomicOr(&supp[t_ >> 5], 1u << (t_ & 31)); } \
          if (16 + 2 * u_ + 1 < ce_) { int t_ = (int)(e2_[u_] >> 16);     atomicOr(&supp[t_ >> 5], 1u << (t_ & 31)); } } } } \
    u64 om_ = __ballot(selme && ((int)cw##s > L)); \
    while (om_) { \
      int j_ = (int)__builtin_ctzll(om_); om_ &= om_ - 1; \
      const int mc_ = base_ + j_; \
      float ax1_ = CX1[mc_], ay1_ = CY1[mc_], ax2_ = CX2[mc_], ay2_ = CY2[mc_], aar_ = CAR[mc_]; \
      for (int c2_ = base_ + 64 + lane; c2_ < n; c2_ += 64) { \
        float ovr_ = iou_ref(ax1_, ay1_, ax2_, ay2_, aar_, CX1[c2_], CY1[c2_], CX2[c2_], CY2[c2_], CAR[c2_]); \
        if (ovr_ > NMS_T) atomicOr(&supp[c2_ >> 5], 1u << (c2_ & 31)); } } } }

__global__ __launch_bounds__(64) void scan_kernel(
    const float* __restrict__ cx1, const float* __restrict__ cy1,
    const float* __restrict__ cx2, const float* __restrict__ cy2,
    const float* __restrict__ car, const int* __restrict__ ncand,
    const u64* __restrict__ diagT, const unsigned* __restrict__ rowcnt,
    const unsigned short* __restrict__ rows_t, int L,
    float* __restrict__ out) {
  const int b = blockIdx.x;
  const int lane = threadIdx.x;
  __shared__ unsigned supp[2 * WPB];
  __shared__ int sel[POST];
  for (int idx = lane; idx < 2 * WPB; idx += 64) supp[idx] = 0u;

  const int n = ncand[b];
  const u64* diagb = diagT + (size_t)b * WPB * 64;
  const unsigned* rcb = rowcnt + (size_t)b * CPAD;
  const unsigned short* rtb = rows_t + (size_t)b * L * CPAD;
  const float* CX1 = cx1 + (size_t)b * CPAD;
  const float* CY1 = cy1 + (size_t)b * CPAD;
  const float* CX2 = cx2 + (size_t)b * CPAD;
  const float* CY2 = cy2 + (size_t)b * CPAD;
  const float* CAR = car + (size_t)b * CPAD;

  const int nw = (n + 63) >> 6;
  int sc = 0;

  DECLW(a0) DECLW(a1) DECLW(a2) DECLW(a3)
  DECLW(b0) DECLW(b1) DECLW(b2) DECLW(b3)

  if (nw > 0) {
    LOADW(a0, 0)
    LOADW(a1, min(1, WPB - 1))
    LOADW(a2, min(2, WPB - 1))
    LOADW(a3, min(3, WPB - 1))
    const int ng = (nw + 3) >> 2;
    for (int g = 0; g < ng && sc < POST; ++g) {
      const int wn = 4 * g + 4;
      LOADW(b0, min(wn + 0, WPB - 1))
      LOADW(b1, min(wn + 1, WPB - 1))
      LOADW(b2, min(wn + 2, WPB - 1))
      LOADW(b3, min(wn + 3, WPB - 1))
      PROCW(a0, 4 * g + 0)
      PROCW(a1, 4 * g + 1)
      PROCW(a2, 4 * g + 2)
      PROCW(a3, 4 * g + 3)
      kwa0 = kwb0; cwa0 = cwb0; p0a0 = p0b0; p1a0 = p1b0;
      kwa1 = kwb1; cwa1 = cwb1; p0a1 = p0b1; p1a1 = p1b1;
      kwa2 = kwb2; cwa2 = cwb2; p0a2 = p0b2; p1a2 = p1b2;
      kwa3 = kwb3; cwa3 = cwb3; p0a3 = p0b3; p1a3 = p1b3;
    }
  }

  float* roib = out + (size_t)b * POST * 4;
  float* maskb = out + (size_t)BATCH * POST * 4 + (size_t)b * POST;
  for (int t = lane; t < POST; t += 64) {
    if (t < sc) {
      int j = sel[t];
      float4 v = make_float4(CX1[j], CY1[j], CX2[j], CY2[j]);
      *(float4*)(roib + (size_t)t * 4) = v;
      maskb[t] = 1.0f;
    } else {
      *(float4*)(roib + (size_t)t * 4) = make_float4(0.f, 0.f, 0.f, 0.f);
      maskb[t] = 0.0f;
    }
  }
}

// ---------------- Fallback path (tiny-ws only) ----------------
__global__ __launch_bounds__(256) void decode_fb_kernel(
    const float* __restrict__ anchors, const float* __restrict__ cls,
    const float* __restrict__ bbox,
    float* __restrict__ bx1, float* __restrict__ by1,
    float* __restrict__ bx2, float* __restrict__ by2,
    unsigned* __restrict__ keys) {
  int i = blockIdx.x * 256 + threadIdx.x;
  if (i >= N_ANCHN) return;
  int b = blockIdx.y;
  float x1, y1, x2, y2; unsigned k;
  decode_one(anchors, cls, bbox, b, i, x1, y1, x2, y2, k);
  size_t o = (size_t)b * NPAD + i;
  bx1[o] = x1; by1[o] = y1; bx2[o] = x2; by2[o] = y2;
  keys[o] = k;
}

__global__ __launch_bounds__(1024) void prep_kernel(
    const unsigned* __restrict__ keys,
    const float* __restrict__ bx1, const float* __restrict__ by1,
    const float* __restrict__ bx2, const float* __restrict__ by2,
    unsigned char* __restrict__ flags,
    float* __restrict__ cx1, float* __restrict__ cy1,
    float* __restrict__ cx2, float* __restrict__ cy2,
    float* __restrict__ car, int* __restrict__ ncand) {
  const int b = blockIdx.x;
  const int tid = threadIdx.x;
  __shared__ unsigned hist[256];
  __shared__ unsigned ssc[1024];
  __shared__ unsigned sh_prefix, sh_k;
  const unsigned* kb = keys + (size_t)b * NPAD;

  if (tid == 0) { sh_prefix = 0u; sh_k = PRE; }
  __syncthreads();

  for (int level = 0; level < 4; ++level) {
    const int shift = 24 - 8 * level;
    if (tid < 256) hist[tid] = 0u;
    __syncthreads();
    unsigned pre = sh_prefix;
    for (int i = tid; i < N_ANCHN; i += 1024) {
      unsigned k = kb[i];
      bool match = (level == 0) || ((k >> (shift + 8)) == (pre >> (shift + 8)));
      if (match) atomicAdd(&hist[(k >> shift) & 255u], 1u);
    }
    __syncthreads();
    if (tid == 0) {
      unsigned kk = sh_k, cum = 0;
      for (int d = 255; d >= 0; --d) {
        unsigned c = hist[d];
        if (cum + c >= kk) { sh_k = kk - cum; sh_prefix = pre | ((unsigned)d << shift); break; }
        cum += c;
      }
    }
    __syncthreads();
  }
  const unsigned T = sh_prefix;

  unsigned local = 0;
  for (int i = tid; i < N_ANCHN; i += 1024) local += (kb[i] > T) ? 1u : 0u;
  ssc[tid] = local;
  __syncthreads();
  for (int off = 512; off > 0; off >>= 1) {
    if (tid < off) ssc[tid] += ssc[tid + off];
    __syncthreads();
  }
  const unsigned slots = PRE - ssc[0];
  __syncthreads();

  const int SEG = (N_ANCHN + 1023) / 1024;
  const float* X1 = bx1 + (size_t)b * NPAD;
  const float* Y1 = by1 + (size_t)b * NPAD;
  const float* X2 = bx2 + (size_t)b * NPAD;
  const float* Y2 = by2 + (size_t)b * NPAD;
  unsigned char* fb = flags + (size_t)b * NPAD;

  {
    int i0 = tid * SEG, i1 = min(N_ANCHN, i0 + SEG);
    unsigned cnt = 0;
    for (int i = i0; i < i1; ++i) cnt += (kb[i] == T) ? 1u : 0u;
    ssc[tid] = cnt;
    __syncthreads();
    for (int off = 1; off < 1024; off <<= 1) {
      unsigned v = (tid >= off) ? ssc[tid - off] : 0u;
      __syncthreads();
      ssc[tid] += v;
      __syncthreads();
    }
    unsigned r = ssc[tid] - cnt;
    for (int i = i0; i < i1; ++i) {
      unsigned k = kb[i];
      bool valid = (__fsub_rn(Y2[i], Y1[i]) >= MINSZ) && (__fsub_rn(X2[i], X1[i]) >= MINSZ);
      bool tie = (k == T);
      bool cand = valid && ((k > T) || (tie && r < slots));
      if (tie) r++;
      fb[i] = cand ? (unsigned char)1 : (unsigned char)0;
    }
  }
  __syncthreads();

  {
    int j0 = tid * SEG, j1 = min(N_ANCHN, j0 + SEG);
    unsigned cnt = 0;
    for (int j = j0; j < j1; ++j) cnt += fb[N_ANCHN - 1 - j];
    ssc[tid] = cnt;
    __syncthreads();
    for (int off = 1; off < 1024; off <<= 1) {
      unsigned v = (tid >= off) ? ssc[tid - off] : 0u;
      __syncthreads();
      ssc[tid] += v;
      __syncthreads();
    }
    unsigned p = ssc[tid] - cnt;
    if (tid == 0) ncand[b] = (int)ssc[1023];
    float* CX1 = cx1 + (size_t)b * CPAD;
    float* CY1 = cy1 + (size_t)b * CPAD;
    float* CX2 = cx2 + (size_t)b * CPAD;
    float* CY2 = cy2 + (size_t)b * CPAD;
    float* CAR = car + (size_t)b * CPAD;
    for (int j = j0; j < j1; ++j) {
      int i = N_ANCHN - 1 - j;
      if (fb[i]) {
        float x1v = X1[i], y1v = Y1[i], x2v = X2[i], y2v = Y2[i];
        CX1[p] = x1v; CY1[p] = y1v; CX2[p] = x2v; CY2[p] = y2v;
        CAR[p] = __fmul_rn(__fadd_rn(__fsub_rn(x2v, x1v), 1.0f),
                           __fadd_rn(__fsub_rn(y2v, y1v), 1.0f));
        p++;
      }
    }
  }
}

__global__ __launch_bounds__(1024) void nms_kernel(
    const float* __restrict__ cx1, const float* __restrict__ cy1,
    const float* __restrict__ cx2, const float* __restrict__ cy2,
    const float* __restrict__ car, const int* __restrict__ ncand,
    float* __restrict__ out) {
  const int b = blockIdx.x;
  const int tid = threadIdx.x;
  __shared__ float sx1[POST], sy1[POST], sx2[POST], sy2[POST], sar[POST];
  __shared__ int Lbuf[1024];
  __shared__ int wcount[16];
  __shared__ int sh_sc;

  const float* CX1 = cx1 + (size_t)b * CPAD;
  const float* CY1 = cy1 + (size_t)b * CPAD;
  const float* CX2 = cx2 + (size_t)b * CPAD;
  const float* CY2 = cy2 + (size_t)b * CPAD;
  const float* CAR = car + (size_t)b * CPAD;
  float* roib = out + (size_t)b * POST * 4;
  float* maskb = out + (size_t)BATCH * POST * 4 + (size_t)b * POST;

  const int n = ncand[b];
  if (tid == 0) sh_sc = 0;
  __syncthreads();
  const int lane = tid & 63;
  const int w = tid >> 6;

  for (int base = 0; base < n; base += 1024) {
    const int c = base + tid;
    bool pass = (c < n);
    float px1 = 0, py1 = 0, px2 = 0, py2 = 0, par = 0;
    if (pass) { px1 = CX1[c]; py1 = CY1[c]; px2 = CX2[c]; py2 = CY2[c]; par = CAR[c]; }
    const int sc0 = sh_sc;

    if (pass) {
      for (int k = 0; k < sc0; ++k) {
        float ovr = iou_ref(sx1[k], sy1[k], sx2[k], sy2[k], sar[k], px1, py1, px2, py2, par);
        if (ovr > NMS_T) { pass = false; break; }
      }
    }

    unsigned long long bal = __ballot(pass);
    if (lane == 0) wcount[w] = (int)__popcll(bal);
    __syncthreads();
    int off = 0;
    for (int q = 0; q < 16; ++q) off += (q < w) ? wcount[q] : 0;
    if (pass) Lbuf[off + (int)__popcll(bal & ((1ULL << lane) - 1ULL))] = c;
    __syncthreads();

    if (tid < 64) {
      int total = 0;
      for (int q = 0; q < 16; ++q) total += wcount[q];
      int sc = sc0;
      for (int g = 0; g < total && sc < POST; g += 64) {
        int idx = (g + lane < total) ? Lbuf[g + lane] : -1;
        float qx1 = 0, qy1 = 0, qx2 = 0, qy2 = 0, qar = 0;
        bool al = (idx >= 0);
        if (al) { qx1 = CX1[idx]; qy1 = CY1[idx]; qx2 = CX2[idx]; qy2 = CY2[idx]; qar = CAR[idx]; }
        for (int k = sc0; k < sc && al; ++k) {
          float ovr = iou_ref(sx1[k], sy1[k], sx2[k], sy2[k], sar[k], qx1, qy1, qx2, qy2, qar);
          if (ovr > NMS_T) al = false;
        }
        unsigned long long alive = __ballot(al);
        while (alive && sc < POST) {
          int j = (int)__builtin_ctzll(alive);
          float jx1 = __shfl(qx1, j), jy1 = __shfl(qy1, j);
          float jx2 = __shfl(qx2, j), jy2 = __shfl(qy2, j), jar = __shfl(qar, j);
          float ovr = iou_ref(jx1, jy1, jx2, jy2, jar, qx1, qy1, qx2, qy2, qar);
          unsigned long long killm = __ballot(ovr > NMS_T);
          alive &= ~killm;
          alive &= ~(1ULL << j);
          if (lane == 0) {
            sx1[sc] = jx1; sy1[sc] = jy1; sx2[sc] = jx2; sy2[sc] = jy2; sar[sc] = jar;
            roib[(size_t)sc * 4 + 0] = jx1;
            roib[(size_t)sc * 4 + 1] = jy1;
            roib[(size_t)sc * 4 + 2] = jx2;
            roib[(size_t)sc * 4 + 3] = jy2;
          }
          sc++;
        }
      }
      if (lane == 0) sh_sc = sc;
    }
    __syncthreads();
    if (sh_sc >= POST) break;
  }
  __syncthreads();

  const int sc = sh_sc;
  for (int t = tid; t < POST; t += 1024) {
    if (t >= sc) {
      roib[(size_t)t * 4 + 0] = 0.f; roib[(size_t)t * 4 + 1] = 0.f;
      roib[(size_t)t * 4 + 2] = 0.f; roib[(size_t)t * 4 + 3] = 0.f;
    }
    maskb[t] = (t < sc) ? 1.0f : 0.0f;
  }
}

extern "C" void kernel_launch(void* const* d_in, const int* in_sizes, int n_in,
                              void* d_out, int out_size, void* d_ws, size_t ws_size,
                              hipStream_t stream) {
  const float* anchors = (const float*)d_in[0];
  const float* cls = (const float*)d_in[1];
  const float* bbox = (const float*)d_in[2];
  float* out = (float*)d_out;
  char* ws = (char*)d_ws;

  // ---- persistent region ----
  size_t o = 0;
  float* cx1 = (float*)(ws + o); o += (size_t)BATCH * CPAD * 4;
  float* cy1 = (float*)(ws + o); o += (size_t)BATCH * CPAD * 4;
  float* cx2 = (float*)(ws + o); o += (size_t)BATCH * CPAD * 4;
  float* cy2 = (float*)(ws + o); o += (size_t)BATCH * CPAD * 4;
  float* car = (float*)(ws + o); o += (size_t)BATCH * CPAD * 4;
  int* ncand = (int*)(ws + o); o += 256;
  u64* diag = (u64*)(ws + o); o += (size_t)BATCH * WPB * 64 * 8;
  unsigned* rowcnt = (unsigned*)(ws + o); o += (size_t)BATCH * CPAD * 4;
  float* wminx1 = (float*)(ws + o); o += (size_t)BATCH * WPB * 4;
  float* wmaxx2 = (float*)(ws + o); o += (size_t)BATCH * WPB * 4;
  float* sx1 = (float*)(ws + o); o += (size_t)BATCH * CPAD * 4;
  float* sy1 = (float*)(ws + o); o += (size_t)BATCH * CPAD * 4;
  float* sx2 = (float*)(ws + o); o += (size_t)BATCH * CPAD * 4;
  float* sy2 = (float*)(ws + o); o += (size_t)BATCH * CPAD * 4;
  float* sar = (float*)(ws + o); o += (size_t)BATCH * CPAD * 4;
  int* sperm = (int*)(ws + o); o += (size_t)BATCH * CPAD * 4;
  size_t overlay = o;     // decode region and rows_t share this space
  unsigned* keys = (unsigned*)(ws + overlay);
  float* bx1 = (float*)(ws + overlay + (size_t)BATCH * NPAD * 4 * 1);
  float* by1 = (float*)(ws + overlay + (size_t)BATCH * NPAD * 4 * 2);
  float* bx2 = (float*)(ws + overlay + (size_t)BATCH * NPAD * 4 * 3);
  float* by2 = (float*)(ws + overlay + (size_t)BATCH * NPAD * 4 * 4);
  size_t decode_bytes = (size_t)BATCH * NPAD * 4 * 5;
  unsigned short* rows_t = (unsigned short*)(ws + overlay);  // build writes AFTER prepsort reads

  int L = 0;
  for (int Ltry = 32; Ltry >= 16; Ltry -= 16) {
    size_t rows_bytes = (size_t)BATCH * Ltry * CPAD * 2;
    size_t need = overlay + (decode_bytes > rows_bytes ? decode_bytes : rows_bytes);
    if (ws_size >= need) { L = Ltry; break; }
  }

  if (L > 0) {
    dim3 dgrid((N_ANCHN + 255) / 256 + 1, BATCH);   // last x-block zeroes diag/rowcnt
    decode_kernel<<<dgrid, 256, 0, stream>>>(anchors, cls, bbox, bx1, by1, bx2, by2,
                                             keys, diag, rowcnt);
    prepsort_kernel<<<BATCH, 1024, 0, stream>>>(keys, bx1, by1, bx2, by2,
                                                cx1, cy1, cx2, cy2, car, ncand,
                                                sx1, sy1, sx2, sy2, sar, sperm,
                                                wminx1, wmaxx2);
    build_kernel<<<dim3(WPB, (WPB + 3) / 4, BATCH), 64, 0, stream>>>(
        sx1, sy1, sx2, sy2, sar, sperm, ncand, wminx1, wmaxx2,
        diag, rowcnt, rows_t, L);
    scan_kernel<<<BATCH, 64, 0, stream>>>(cx1, cy1, cx2, cy2, car, ncand,
                                          diag, rowcnt, rows_t, L, out);
  } else {
    // tiny-ws fallback: round-1 layout + kernels
    size_t f = 0;
    unsigned* fkeys = (unsigned*)(ws + f); f += (size_t)BATCH * NPAD * 4;
    float* fbx1 = (float*)(ws + f); f += (size_t)BATCH * NPAD * 4;
    float* fby1 = (float*)(ws + f); f += (size_t)BATCH * NPAD * 4;
    float* fbx2 = (float*)(ws + f); f += (size_t)BATCH * NPAD * 4;
    float* fby2 = (float*)(ws + f); f += (size_t)BATCH * NPAD * 4;
    float* fcx1 = (float*)(ws + f); f += (size_t)BATCH * CPAD * 4;
    float* fcy1 = (float*)(ws + f); f += (size_t)BATCH * CPAD * 4;
    float* fcx2 = (float*)(ws + f); f += (size_t)BATCH * CPAD * 4;
    float* fcy2 = (float*)(ws + f); f += (size_t)BATCH * CPAD * 4;
    float* fcar = (float*)(ws + f); f += (size_t)BATCH * CPAD * 4;
    unsigned char* fflags = (unsigned char*)(ws + f); f += (size_t)BATCH * NPAD;
    int* fncand = (int*)(ws + f); f += 256;

    dim3 dgrid((N_ANCHN + 255) / 256, BATCH);
    decode_fb_kernel<<<dgrid, 256, 0, stream>>>(anchors, cls, bbox, fbx1, fby1, fbx2, fby2, fkeys);
    prep_kernel<<<BATCH, 1024, 0, stream>>>(fkeys, fbx1, fby1, fbx2, fby2, fflags,
                                            fcx1, fcy1, fcx2, fcy2, fcar, fncand);
    nms_kernel<<<BATCH, 1024, 0, stream>>>(fcx1, fcy1, fcx2, fcy2, fcar, fncand, out);
  }
}

// Round 6
// 543.463 us; speedup vs baseline: 1.1867x; 1.1867x over previous
//
#include <hip/hip_runtime.h>
#include <math.h>

#define N_ANCHN 18675
#define NPAD    18688
#define BATCH   16
#define PRE     12000
#define CPAD    12032
#define WPB     188      // CPAD/64 words per row
#define POST    2000
#define NMS_T   0.7f
#define IMGX    1333.0f
#define IMGY    402.0f
#define MINSZ   16.0f
#define NBUCK   256
#define KINV    0x007FFFFFu   // key_of(-inf)
#define MLCAP   12288

typedef unsigned long long u64;

__device__ __forceinline__ unsigned key_of(float f) {
  unsigned u = __float_as_uint(f);
  return (u & 0x80000000u) ? ~u : (u | 0x80000000u);
}

// Reference-exact IoU: inter/(a_area + b_area - inter), +1 box convention, no FMA.
__device__ __forceinline__ float iou_ref(float ax1, float ay1, float ax2, float ay2, float aar,
                                         float bx1, float by1, float bx2, float by2, float bar) {
  float xx1 = fmaxf(ax1, bx1);
  float yy1 = fmaxf(ay1, by1);
  float xx2 = fminf(ax2, bx2);
  float yy2 = fminf(ay2, by2);
  float iw = fmaxf(0.0f, __fadd_rn(__fsub_rn(xx2, xx1), 1.0f));
  float ih = fmaxf(0.0f, __fadd_rn(__fsub_rn(yy2, yy1), 1.0f));
  float inter = __fmul_rn(iw, ih);
  return __fdiv_rn(inter, __fsub_rn(__fadd_rn(aar, bar), inter));
}

// Decision-identical to (iou_ref > 0.7): band bounds 0.395/0.43 vs exact 0.41176
// leave ~4% slack against <=1e-6 float rounding; middle band recomputes ref-exact.
__device__ __forceinline__ bool hit_test(float ix1, float iy1, float ix2, float iy2, float iar,
                                         float jx1, float jy1, float jx2, float jy2, float jar) {
  float xx1 = fmaxf(ix1, jx1);
  float yy1 = fmaxf(iy1, jy1);
  float xx2 = fminf(ix2, jx2);
  float yy2 = fminf(iy2, jy2);
  float iw = fmaxf(0.0f, __fadd_rn(__fsub_rn(xx2, xx1), 1.0f));
  float ih = fmaxf(0.0f, __fadd_rn(__fsub_rn(yy2, yy1), 1.0f));
  float inter = __fmul_rn(iw, ih);
  float S = __fadd_rn(iar, jar);
  if (inter >= __fmul_rn(0.43f, S)) return true;
  if (inter <= __fmul_rn(0.395f, S)) return false;
  return __fdiv_rn(inter, __fsub_rn(S, inter)) > NMS_T;
}

// Same-word pairs stored TRANSPOSED — diagb[word*64 + lo] bit hi means
// "lo kills hi" (kills-BY-lo mask). Lets scan's greedy chain fetch the kill
// mask of a selected box with 2 readlanes instead of a per-iteration ballot.
__device__ __forceinline__ void emit_hit(int lo, int hi, u64* diagb, unsigned* rcb,
                                         unsigned short* rtb, int L) {
  if ((hi >> 6) == (lo >> 6)) {
    atomicOr(&diagb[(size_t)(lo >> 6) * 64 + (lo & 63)], 1ull << (hi & 63));
  } else {
    unsigned slot = atomicAdd(&rcb[lo], 1u);
    if ((int)slot < L) rtb[(size_t)lo * L + slot] = (unsigned short)hi;
  }
}

__device__ __forceinline__ void decode_one(
    const float* __restrict__ anchors, const float* __restrict__ cls,
    const float* __restrict__ bbox, int b, int i,
    float& x1, float& y1, float& x2, float& y2, unsigned& key) {
  float4 A = *(const float4*)(anchors + (size_t)i * 4);
  float ah = __fsub_rn(A.w, A.y);
  float aw = __fsub_rn(A.z, A.x);
  float acy = __fadd_rn(A.y, __fmul_rn(0.5f, ah));
  float acx = __fadd_rn(A.x, __fmul_rn(0.5f, aw));

  float4 P = *(const float4*)(bbox + ((size_t)b * N_ANCHN + i) * 4);
  float dx = P.x, dy = P.y, dw = P.z, dh = P.w;

  float cy = __fadd_rn(__fmul_rn(dy, ah), acy);
  float cx = __fadd_rn(__fmul_rn(dx, aw), acx);
  float eh = (float)exp((double)dh);
  float ew = (float)exp((double)dw);
  float h = __fmul_rn(eh, ah);
  float w = __fmul_rn(ew, aw);

  x1 = fminf(fmaxf(__fsub_rn(cx, __fmul_rn(0.5f, w)), 0.0f), IMGX);
  y1 = fminf(fmaxf(__fsub_rn(cy, __fmul_rn(0.5f, h)), 0.0f), IMGY);
  x2 = fminf(fmaxf(__fadd_rn(cx, __fmul_rn(0.5f, w)), 0.0f), IMGX);
  y2 = fminf(fmaxf(__fadd_rn(cy, __fmul_rn(0.5f, h)), 0.0f), IMGY);

  bool valid = (__fsub_rn(y2, y1) >= MINSZ) && (__fsub_rn(x2, x1) >= MINSZ);
  float s = valid ? cls[(size_t)b * (2 * N_ANCHN) + 2 * i + 1] : -INFINITY;
  key = key_of(s);
}

// ---------------- Kernel 1: full-grid decode (+ zeroing column) ----------------
__global__ __launch_bounds__(256) void decode_kernel(
    const float* __restrict__ anchors, const float* __restrict__ cls,
    const float* __restrict__ bbox,
    float* __restrict__ bx1, float* __restrict__ by1,
    float* __restrict__ bx2, float* __restrict__ by2,
    unsigned* __restrict__ keys,
    u64* __restrict__ diag, unsigned* __restrict__ rowcnt) {
  const int bx = blockIdx.x;
  const int b = blockIdx.y;
  if (bx == gridDim.x - 1) {
    u64* dz = diag + (size_t)b * WPB * 64;
    for (int i = threadIdx.x; i < WPB * 64; i += 256) dz[i] = 0ull;
    unsigned* rz = rowcnt + (size_t)b * CPAD;
    for (int i = threadIdx.x; i < CPAD; i += 256) rz[i] = 0u;
    return;
  }
  int i = bx * 256 + threadIdx.x;
  if (i >= N_ANCHN) return;
  float x1, y1, x2, y2; unsigned k;
  decode_one(anchors, cls, bbox, b, i, x1, y1, x2, y2, k);
  size_t o = (size_t)b * NPAD + i;
  bx1[o] = x1; by1[o] = y1; bx2[o] = x2; by2[o] = y2;
  keys[o] = k;
}

// ---------------- Kernel 2: prep (radix-select + compaction) + x-sort ----------------
__global__ __launch_bounds__(1024) void prepsort_kernel(
    const unsigned* __restrict__ keys,
    const float* __restrict__ bx1, const float* __restrict__ by1,
    const float* __restrict__ bx2, const float* __restrict__ by2,
    float* __restrict__ cx1, float* __restrict__ cy1,
    float* __restrict__ cx2, float* __restrict__ cy2,
    float* __restrict__ car, int* __restrict__ ncand,
    float* __restrict__ sx1, float* __restrict__ sy1,
    float* __restrict__ sx2, float* __restrict__ sy2,
    float* __restrict__ sar, int* __restrict__ sperm,
    float* __restrict__ wminx1, float* __restrict__ wmaxx2) {
  const int b = blockIdx.x;
  const int tid = threadIdx.x;
  const int lane = tid & 63;
  const int wv = tid >> 6;
  __shared__ unsigned hist[16][256];
  __shared__ unsigned mh[256];
  __shared__ unsigned wsum[16];
  __shared__ unsigned bh[NBUCK];
  __shared__ unsigned boff[NBUCK];
  __shared__ unsigned char fb[NPAD];
  __shared__ unsigned short mlist[MLCAP];
  __shared__ unsigned sh_prefix, sh_k, sh_n, sh_mcount;
  const unsigned* kb = keys + (size_t)b * NPAD;

  if (tid == 0) { sh_prefix = 0u; sh_k = PRE; sh_mcount = 0u; }
  __syncthreads();

  // ---- radix level 0 (full scan) ----
  {
    for (int idx = tid; idx < 16 * 256; idx += 1024) ((unsigned*)hist)[idx] = 0u;
    __syncthreads();
    for (int i = tid; i < N_ANCHN; i += 1024)
      atomicAdd(&hist[wv][kb[i] >> 24], 1u);
    __syncthreads();
    if (tid < 256) {
      unsigned s = 0;
#pragma unroll
      for (int q = 0; q < 16; ++q) s += hist[q][tid];
      mh[tid] = s;
    }
    __syncthreads();
    if (tid == 0) {
      unsigned kk = sh_k, cum = 0;
      for (int d = 255; d >= 0; --d) {
        unsigned c = mh[d];
        if (cum + c >= kk) { sh_k = kk - cum; sh_prefix = (unsigned)d << 24; break; }
        cum += c;
      }
    }
    __syncthreads();
  }

  // ---- compact indices matching top byte (narrows levels 1-3) ----
  {
    unsigned b0 = sh_prefix >> 24;
    for (int i = tid; i < N_ANCHN; i += 1024) {
      if ((kb[i] >> 24) == b0) {
        unsigned p = atomicAdd(&sh_mcount, 1u);
        if (p < MLCAP) mlist[p] = (unsigned short)i;
      }
    }
  }
  __syncthreads();
  const bool useList = (sh_mcount <= (unsigned)MLCAP);
  const unsigned mcount = min(sh_mcount, (unsigned)MLCAP);

  // ---- radix levels 1-3 (list-narrowed; exact fallback) ----
  for (int level = 1; level < 4; ++level) {
    const int shift = 24 - 8 * level;
    for (int idx = tid; idx < 16 * 256; idx += 1024) ((unsigned*)hist)[idx] = 0u;
    __syncthreads();
    unsigned pre = sh_prefix;
    if (useList) {
      for (int idx = tid; idx < (int)mcount; idx += 1024) {
        unsigned k = kb[mlist[idx]];
        if ((k >> (shift + 8)) == (pre >> (shift + 8)))
          atomicAdd(&hist[wv][(k >> shift) & 255u], 1u);
      }
    } else {
      for (int i = tid; i < N_ANCHN; i += 1024) {
        unsigned k = kb[i];
        if ((k >> (shift + 8)) == (pre >> (shift + 8)))
          atomicAdd(&hist[wv][(k >> shift) & 255u], 1u);
      }
    }
    __syncthreads();
    if (tid < 256) {
      unsigned s = 0;
#pragma unroll
      for (int q = 0; q < 16; ++q) s += hist[q][tid];
      mh[tid] = s;
    }
    __syncthreads();
    if (tid == 0) {
      unsigned kk = sh_k, cum = 0;
      for (int d = 255; d >= 0; --d) {
        unsigned c = mh[d];
        if (cum + c >= kk) { sh_k = kk - cum; sh_prefix = pre | ((unsigned)d << shift); break; }
        cum += c;
      }
    }
    __syncthreads();
  }
  const unsigned T = sh_prefix;
  // radix-select invariant: after the last level, sh_k = PRE - count(keys > T) = tie slots
  const unsigned slots = sh_k;

  const int SEG = (N_ANCHN + 1023) / 1024;

  // ---- flags with stable tie-rank (keys only; wave-scan for tie prefix) ----
  {
    int i0 = tid * SEG, i1 = min(N_ANCHN, i0 + SEG);
    unsigned cnt = 0;
    for (int i = i0; i < i1; ++i) cnt += (kb[i] == T) ? 1u : 0u;
    unsigned v = cnt;
#pragma unroll
    for (int d = 1; d < 64; d <<= 1) {
      unsigned y = __shfl_up(v, d, 64);
      if (lane >= d) v += y;
    }
    if (lane == 63) wsum[wv] = v;
    __syncthreads();
    if (tid == 0) {
      unsigned acc = 0;
#pragma unroll
      for (int q = 0; q < 16; ++q) { unsigned t = wsum[q]; wsum[q] = acc; acc += t; }
    }
    __syncthreads();
    unsigned r = wsum[wv] + v - cnt;   // exclusive tie rank base
    for (int i = i0; i < i1; ++i) {
      unsigned k = kb[i];
      bool tie = (k == T);
      bool cand = (k > T) || (tie && T > KINV && r < slots);
      if (tie) r++;
      fb[i] = cand ? (unsigned char)1 : (unsigned char)0;
    }
  }
  __syncthreads();

  // ---- ordered compaction: descending anchor index (wave-scan prefix) ----
  const float* X1 = bx1 + (size_t)b * NPAD;
  const float* Y1 = by1 + (size_t)b * NPAD;
  const float* X2 = bx2 + (size_t)b * NPAD;
  const float* Y2 = by2 + (size_t)b * NPAD;
  {
    int j0 = tid * SEG, j1 = min(N_ANCHN, j0 + SEG);
    unsigned cnt = 0;
    for (int j = j0; j < j1; ++j) cnt += fb[N_ANCHN - 1 - j];
    unsigned v = cnt;
#pragma unroll
    for (int d = 1; d < 64; d <<= 1) {
      unsigned y = __shfl_up(v, d, 64);
      if (lane >= d) v += y;
    }
    if (lane == 63) wsum[wv] = v;
    __syncthreads();
    if (tid == 0) {
      unsigned acc = 0;
#pragma unroll
      for (int q = 0; q < 16; ++q) { unsigned t = wsum[q]; wsum[q] = acc; acc += t; }
      sh_n = acc;
    }
    __syncthreads();
    unsigned p = wsum[wv] + v - cnt;
    if (tid == 0) ncand[b] = (int)sh_n;
    float* CX1 = cx1 + (size_t)b * CPAD;
    float* CY1 = cy1 + (size_t)b * CPAD;
    float* CX2 = cx2 + (size_t)b * CPAD;
    float* CY2 = cy2 + (size_t)b * CPAD;
    float* CAR = car + (size_t)b * CPAD;
    for (int j = j0; j < j1; ++j) {
      int i = N_ANCHN - 1 - j;
      if (fb[i]) {
        float x1v = X1[i], y1v = Y1[i], x2v = X2[i], y2v = Y2[i];
        CX1[p] = x1v; CY1[p] = y1v; CX2[p] = x2v; CY2[p] = y2v;
        CAR[p] = __fmul_rn(__fadd_rn(__fsub_rn(x2v, x1v), 1.0f),
                           __fadd_rn(__fsub_rn(y2v, y1v), 1.0f));
        p++;
      }
    }
  }
  __syncthreads();
  const int n = (int)sh_n;

  // ---- 256-bucket x1 sort + per-word aggregates (R7-proven layout) ----
  const float scale = (float)NBUCK / 1334.0f;
  const float* CX1 = cx1 + (size_t)b * CPAD;
  const float* CY1 = cy1 + (size_t)b * CPAD;
  const float* CX2 = cx2 + (size_t)b * CPAD;
  const float* CY2 = cy2 + (size_t)b * CPAD;
  const float* CAR = car + (size_t)b * CPAD;
  float* SX1 = sx1 + (size_t)b * CPAD;
  float* SY1 = sy1 + (size_t)b * CPAD;
  float* SX2 = sx2 + (size_t)b * CPAD;
  float* SY2 = sy2 + (size_t)b * CPAD;
  float* SAR = sar + (size_t)b * CPAD;
  int* SP = sperm + (size_t)b * CPAD;

  if (tid < NBUCK) bh[tid] = 0u;
  __syncthreads();
  for (int i = tid; i < n; i += 1024) {
    int q = (int)(CX1[i] * scale);
    q = q < 0 ? 0 : (q > NBUCK - 1 ? NBUCK - 1 : q);
    atomicAdd(&bh[q], 1u);
  }
  __syncthreads();
  if (tid < 64) {
    unsigned carry = 0;
    for (int c = 0; c < 4; ++c) {
      unsigned own = bh[c * 64 + tid];
      unsigned v = own;
      for (int d = 1; d < 64; d <<= 1) {
        unsigned y = __shfl_up(v, d, 64);
        if (tid >= d) v += y;
      }
      boff[c * 64 + tid] = carry + v - own;
      carry += __shfl(v, 63, 64);
    }
  }
  __syncthreads();
  for (int i = tid; i < n; i += 1024) {
    float x1v = CX1[i];
    int q = (int)(x1v * scale);
    q = q < 0 ? 0 : (q > NBUCK - 1 ? NBUCK - 1 : q);
    unsigned p = atomicAdd(&boff[q], 1u);
    SX1[p] = x1v; SY1[p] = CY1[i]; SX2[p] = CX2[i]; SY2[p] = CY2[i];
    SAR[p] = CAR[i]; SP[p] = i;
  }
  for (int i = n + tid; i < CPAD; i += 1024) {
    SX1[i] = 1e30f; SY1[i] = 1e30f; SX2[i] = -1e30f; SY2[i] = -1e30f;
    SAR[i] = 1.0f; SP[i] = 0;
  }
  __syncthreads();
  // wave-parallel per-word aggregates: wave wv handles words wv, wv+16, ...
  for (int w = wv; w < WPB; w += 16) {
    float mn = SX1[64 * w + lane];
    float mx = SX2[64 * w + lane];
#pragma unroll
    for (int d = 32; d > 0; d >>= 1) {
      mn = fminf(mn, __shfl_xor(mn, d, 64));
      mx = fmaxf(mx, __shfl_xor(mx, d, 64));
    }
    if (lane == 0) {
      wminx1[(size_t)b * WPB + w] = mn;
      wmaxx2[(size_t)b * WPB + w] = mx;
    }
  }
}

// ---------------- Kernel 3: transposed banded build, 1-wave blocks, 4 words/wave ----------------
// Block = 1 wave = (row word R, column group G of 4 words). Each lane holds 4
// columns (words 4G..4G+3) in registers; the loop iterates R's rows (wave-
// uniform broadcast from LDS, 2 reads/row feeding 4 hit_tests), with the NEXT
// row's broadcasts prefetched before the current row's tests execute so the
// ~120-cyc LDS latency hides under the VALU work. Per-(row,word) band test
// rx2+2 >= WMN[w] and dedup (w>R | lane>k) are unchanged from the proven R2
// kernel -> identical hit set.
__global__ __launch_bounds__(64) void build_kernel(
    const float* __restrict__ sx1, const float* __restrict__ sy1,
    const float* __restrict__ sx2, const float* __restrict__ sy2,
    const float* __restrict__ sar, const int* __restrict__ sperm,
    const int* __restrict__ ncand,
    const float* __restrict__ wminx1, const float* __restrict__ wmaxx2,
    u64* __restrict__ diagT, unsigned* __restrict__ rowcnt,
    unsigned short* __restrict__ rows_t, int L) {
  const int R = blockIdx.x, G = blockIdx.y, b = blockIdx.z;
  const int n = ncand[b];
  if (64 * R >= n) return;
  if (4 * G + 3 < R) return;        // whole group below row word -> dedup always false
  const float* WMN = wminx1 + (size_t)b * WPB;
  const float rlim = __fadd_rn(wmaxx2[(size_t)b * WPB + R], 2.0f);

  const int w0 = 4 * G;
  const float wmn0 = WMN[w0], wmn1 = WMN[w0 + 1], wmn2 = WMN[w0 + 2], wmn3 = WMN[w0 + 3];
  // pad words have wmn=1e30 > rlim -> auto-invalid
  const bool v0 = (w0     >= R) && (wmn0 <= rlim);
  const bool v1 = (w0 + 1 >= R) && (wmn1 <= rlim);
  const bool v2 = (w0 + 2 >= R) && (wmn2 <= rlim);
  const bool v3 = (w0 + 3 >= R) && (wmn3 <= rlim);
  if (!(v0 | v1 | v2 | v3)) return;

  const float* SX1 = sx1 + (size_t)b * CPAD;
  const float* SY1 = sy1 + (size_t)b * CPAD;
  const float* SX2 = sx2 + (size_t)b * CPAD;
  const float* SY2 = sy2 + (size_t)b * CPAD;
  const float* SAR = sar + (size_t)b * CPAD;
  const int* SP = sperm + (size_t)b * CPAD;

  const int lane = threadIdx.x;

  // stage the 64 rows of word R: box (float4) + packed {area, sperm} (float2)
  __shared__ float4 rbv[64];
  __shared__ float2 ras[64];
  float rx2own;
  {
    int i = 64 * R + lane;
    float4 v = make_float4(SX1[i], SY1[i], SX2[i], SY2[i]);
    rbv[lane] = v;
    ras[lane] = make_float2(SAR[i], __int_as_float(SP[i]));
    rx2own = v.z;
  }

  // this wave's 4 columns per lane, in registers (loads skipped for invalid words)
  float c0x1 = 1e30f, c0y1 = 0.f, c0x2 = 0.f, c0y2 = 0.f, c0ar = 1.f; int c0sp = 0;
  float c1x1 = 1e30f, c1y1 = 0.f, c1x2 = 0.f, c1y2 = 0.f, c1ar = 1.f; int c1sp = 0;
  float c2x1 = 1e30f, c2y1 = 0.f, c2x2 = 0.f, c2y2 = 0.f, c2ar = 1.f; int c2sp = 0;
  float c3x1 = 1e30f, c3y1 = 0.f, c3x2 = 0.f, c3y2 = 0.f, c3ar = 1.f; int c3sp = 0;
  if (v0) { int j = 64 * w0 + lane;
    c0x1 = SX1[j]; c0y1 = SY1[j]; c0x2 = SX2[j]; c0y2 = SY2[j]; c0ar = SAR[j]; c0sp = SP[j]; }
  if (v1) { int j = 64 * (w0 + 1) + lane;
    c1x1 = SX1[j]; c1y1 = SY1[j]; c1x2 = SX2[j]; c1y2 = SY2[j]; c1ar = SAR[j]; c1sp = SP[j]; }
  if (v2) { int j = 64 * (w0 + 2) + lane;
    c2x1 = SX1[j]; c2y1 = SY1[j]; c2x2 = SX2[j]; c2y2 = SY2[j]; c2ar = SAR[j]; c2sp = SP[j]; }
  if (v3) { int j = 64 * (w0 + 3) + lane;
    c3x1 = SX1[j]; c3y1 = SY1[j]; c3x2 = SX2[j]; c3y2 = SY2[j]; c3ar = SAR[j]; c3sp = SP[j]; }
  __syncthreads();   // orders LDS writes before dynamic-index reads (1-wave: ~free)

  // active-row mask from the loosest (lowest-wmn) valid word
  const float wmnlo = v0 ? wmn0 : (v1 ? wmn1 : (v2 ? wmn2 : wmn3));
  u64 a = __ballot(rx2own >= __fsub_rn(wmnlo, 2.0f));
  if (!a) return;

  const float wmn0m2 = __fsub_rn(wmn0, 2.0f);
  const float wmn1m2 = __fsub_rn(wmn1, 2.0f);
  const float wmn2m2 = __fsub_rn(wmn2, 2.0f);
  const float wmn3m2 = __fsub_rn(wmn3, 2.0f);
  const bool g0 = (w0 > R),     e0 = (w0 == R);
  const bool g1 = (w0 + 1 > R), e1 = (w0 + 1 == R);
  const bool g2 = (w0 + 2 > R), e2 = (w0 + 2 == R);
  const bool g3 = (w0 + 3 > R), e3 = (w0 + 3 == R);

  u64* diagb = diagT + (size_t)b * WPB * 64;
  unsigned* rcb = rowcnt + (size_t)b * CPAD;
  unsigned short* rtb = rows_t + (size_t)b * L * CPAD;

  int k = (int)__builtin_ctzll(a);
  float4 RB = rbv[k];
  float2 AS = ras[k];
  while (true) {
    a &= a - 1;
    const int kn = a ? (int)__builtin_ctzll(a) : 0;
    const float4 RBn = rbv[kn];      // prefetch next row (dummy k=0 when done)
    const float2 ASn = ras[kn];
    const float rx2k = RB.z;
    const float rark = AS.x;
    const int rsp = __float_as_int(AS.y);
    if (v0 && rx2k >= wmn0m2) {
      bool dd = g0 | (e0 & (lane > k));
      if (dd && hit_test(RB.x, RB.y, RB.z, RB.w, rark, c0x1, c0y1, c0x2, c0y2, c0ar)) {
        int lo = min(rsp, c0sp), hi = max(rsp, c0sp);
        emit_hit(lo, hi, diagb, rcb, rtb, L);
      }
    }
    if (v1 && rx2k >= wmn1m2) {
      bool dd = g1 | (e1 & (lane > k));
      if (dd && hit_test(RB.x, RB.y, RB.z, RB.w, rark, c1x1, c1y1, c1x2, c1y2, c1ar)) {
        int lo = min(rsp, c1sp), hi = max(rsp, c1sp);
        emit_hit(lo, hi, diagb, rcb, rtb, L);
      }
    }
    if (v2 && rx2k >= wmn2m2) {
      bool dd = g2 | (e2 & (lane > k));
      if (dd && hit_test(RB.x, RB.y, RB.z, RB.w, rark, c2x1, c2y1, c2x2, c2y2, c2ar)) {
        int lo = min(rsp, c2sp), hi = max(rsp, c2sp);
        emit_hit(lo, hi, diagb, rcb, rtb, L);
      }
    }
    if (v3 && rx2k >= wmn3m2) {
      bool dd = g3 | (e3 & (lane > k));
      if (dd && hit_test(RB.x, RB.y, RB.z, RB.w, rark, c3x1, c3y1, c3x2, c3y2, c3ar)) {
        int lo = min(rsp, c3sp), hi = max(rsp, c3sp);
        emit_hit(lo, hi, diagb, rcb, rtb, L);
      }
    }
    if (!a) break;
    k = kn; RB = RBn; AS = ASn;
  }
}

// ---------------- Kernel 4: ballot-free scalar-chain greedy NMS ----------------
// kw is kills-BY-lane (transposed diag). The greedy chain per word is pure
// uniform arithmetic: j = ctz(act); kj = readlane(kw, j); act &= ~(kj|bit j)
// — zero ballots / exec juggling per selection. Selections recorded batched
// after the chain via rank = popcount(selw & below). supp is u64/word.
// R6 FIX: readlane returns int — cast through unsigned before widening to u64
// (R5 sign-extended the low word, wrongly killing lanes 32-63).
#define DECLW(s) u64 kw##s; unsigned cw##s; uint4 p0##s, p1##s;
#define LOADW(s, wexp) { int w_ = (wexp); int c_ = 64 * w_ + lane; \
  kw##s = diagb[(size_t)w_ * 64 + lane]; cw##s = rcb[c_]; \
  const uint4* rp_ = (const uint4*)(rtb + (size_t)c_ * L); p0##s = rp_[0]; p1##s = rp_[1]; }
#define PROCW(s, wexp) { int w_ = (wexp); \
  if (w_ < nw && sc < POST) { \
    const int base_ = 64 * w_; const int myc_ = base_ + lane; \
    const u64 suppw_ = supp[w_]; \
    const bool alv_ = (myc_ < n) && !((suppw_ >> lane) & 1ull); \
    u64 act_ = __ballot(alv_); \
    u64 selw_ = 0ull; \
    const int scb_ = sc; \
    const unsigned klo_ = (unsigned)kw##s, khi_ = (unsigned)(kw##s >> 32); \
    while (act_ && sc < POST) { \
      const int j_ = (int)__builtin_ctzll(act_); \
      const u64 kj_ = ((u64)(unsigned)__builtin_amdgcn_readlane((int)khi_, j_) << 32) | \
                      (u64)(unsigned)__builtin_amdgcn_readlane((int)klo_, j_); \
      selw_ |= 1ull << j_; sc++; \
      act_ &= ~(kj_ | (1ull << j_)); } \
    const bool selme_ = ((selw_ >> lane) & 1ull) != 0ull; \
    if (selme_) { \
      const int rank_ = scb_ + (int)__popcll(selw_ & ((1ull << lane) - 1ull)); \
      sel[rank_] = myc_; \
      const int ce_ = min((int)cw##s, L); \
      uint4 p2_ = {0,0,0,0}, p3_ = {0,0,0,0}; \
      if (ce_ > 16) { \
        const uint4* rp_ = (const uint4*)(rtb + (size_t)myc_ * L); \
        p2_ = rp_[2]; p3_ = rp_[3]; \
      } \
      unsigned ev_[8] = {p0##s.x, p0##s.y, p0##s.z, p0##s.w, p1##s.x, p1##s.y, p1##s.z, p1##s.w}; \
      _Pragma("unroll") \
      for (int u_ = 0; u_ < 8; ++u_) { \
        if (2 * u_ < ce_)     { int t_ = (int)(ev_[u_] & 0xffffu); atomicOr(&supp[t_ >> 6], 1ull << (t_ & 63)); } \
        if (2 * u_ + 1 < ce_) { int t_ = (int)(ev_[u_] >> 16);     atomicOr(&supp[t_ >> 6], 1ull << (t_ & 63)); } } \
      if (ce_ > 16) { \
        unsigned e2_[8] = {p2_.x, p2_.y, p2_.z, p2_.w, p3_.x, p3_.y, p3_.z, p3_.w}; \
        _Pragma("unroll") \
        for (int u_ = 0; u_ < 8; ++u_) { \
          if (16 + 2 * u_ < ce_)     { int t_ = (int)(e2_[u_] & 0xffffu); atomicOr(&supp[t_ >> 6], 1ull << (t_ & 63)); } \
          if (16 + 2 * u_ + 1 < ce_) { int t_ = (int)(e2_[u_] >> 16);     atomicOr(&supp[t_ >> 6], 1ull << (t_ & 63)); } } } } \
    u64 om_ = __ballot(selme_ && ((int)cw##s > L)); \
    while (om_) { \
      int j_ = (int)__builtin_ctzll(om_); om_ &= om_ - 1; \
      const int mc_ = base_ + j_; \
      float ax1_ = CX1[mc_], ay1_ = CY1[mc_], ax2_ = CX2[mc_], ay2_ = CY2[mc_], aar_ = CAR[mc_]; \
      for (int c2_ = base_ + 64 + lane; c2_ < n; c2_ += 64) { \
        float ovr_ = iou_ref(ax1_, ay1_, ax2_, ay2_, aar_, CX1[c2_], CY1[c2_], CX2[c2_], CY2[c2_], CAR[c2_]); \
        if (ovr_ > NMS_T) atomicOr(&supp[c2_ >> 6], 1ull << (c2_ & 63)); } } } }

__global__ __launch_bounds__(64) void scan_kernel(
    const float* __restrict__ cx1, const float* __restrict__ cy1,
    const float* __restrict__ cx2, const float* __restrict__ cy2,
    const float* __restrict__ car, const int* __restrict__ ncand,
    const u64* __restrict__ diagT, const unsigned* __restrict__ rowcnt,
    const unsigned short* __restrict__ rows_t, int L,
    float* __restrict__ out) {
  const int b = blockIdx.x;
  const int lane = threadIdx.x;
  __shared__ u64 supp[WPB];
  __shared__ int sel[POST];
  for (int idx = lane; idx < WPB; idx += 64) supp[idx] = 0ull;

  const int n = ncand[b];
  const u64* diagb = diagT + (size_t)b * WPB * 64;
  const unsigned* rcb = rowcnt + (size_t)b * CPAD;
  const unsigned short* rtb = rows_t + (size_t)b * L * CPAD;
  const float* CX1 = cx1 + (size_t)b * CPAD;
  const float* CY1 = cy1 + (size_t)b * CPAD;
  const float* CX2 = cx2 + (size_t)b * CPAD;
  const float* CY2 = cy2 + (size_t)b * CPAD;
  const float* CAR = car + (size_t)b * CPAD;

  const int nw = (n + 63) >> 6;
  int sc = 0;

  DECLW(a0) DECLW(a1) DECLW(a2) DECLW(a3)
  DECLW(b0) DECLW(b1) DECLW(b2) DECLW(b3)

  if (nw > 0) {
    LOADW(a0, 0)
    LOADW(a1, min(1, WPB - 1))
    LOADW(a2, min(2, WPB - 1))
    LOADW(a3, min(3, WPB - 1))
    const int ng = (nw + 3) >> 2;
    for (int g = 0; g < ng && sc < POST; ++g) {
      const int wn = 4 * g + 4;
      LOADW(b0, min(wn + 0, WPB - 1))
      LOADW(b1, min(wn + 1, WPB - 1))
      LOADW(b2, min(wn + 2, WPB - 1))
      LOADW(b3, min(wn + 3, WPB - 1))
      PROCW(a0, 4 * g + 0)
      PROCW(a1, 4 * g + 1)
      PROCW(a2, 4 * g + 2)
      PROCW(a3, 4 * g + 3)
      kwa0 = kwb0; cwa0 = cwb0; p0a0 = p0b0; p1a0 = p1b0;
      kwa1 = kwb1; cwa1 = cwb1; p0a1 = p0b1; p1a1 = p1b1;
      kwa2 = kwb2; cwa2 = cwb2; p0a2 = p0b2; p1a2 = p1b2;
      kwa3 = kwb3; cwa3 = cwb3; p0a3 = p0b3; p1a3 = p1b3;
    }
  }

  float* roib = out + (size_t)b * POST * 4;
  float* maskb = out + (size_t)BATCH * POST * 4 + (size_t)b * POST;
  for (int t = lane; t < POST; t += 64) {
    if (t < sc) {
      int j = sel[t];
      float4 v = make_float4(CX1[j], CY1[j], CX2[j], CY2[j]);
      *(float4*)(roib + (size_t)t * 4) = v;
      maskb[t] = 1.0f;
    } else {
      *(float4*)(roib + (size_t)t * 4) = make_float4(0.f, 0.f, 0.f, 0.f);
      maskb[t] = 0.0f;
    }
  }
}

// ---------------- Fallback path (tiny-ws only) ----------------
__global__ __launch_bounds__(256) void decode_fb_kernel(
    const float* __restrict__ anchors, const float* __restrict__ cls,
    const float* __restrict__ bbox,
    float* __restrict__ bx1, float* __restrict__ by1,
    float* __restrict__ bx2, float* __restrict__ by2,
    unsigned* __restrict__ keys) {
  int i = blockIdx.x * 256 + threadIdx.x;
  if (i >= N_ANCHN) return;
  int b = blockIdx.y;
  float x1, y1, x2, y2; unsigned k;
  decode_one(anchors, cls, bbox, b, i, x1, y1, x2, y2, k);
  size_t o = (size_t)b * NPAD + i;
  bx1[o] = x1; by1[o] = y1; bx2[o] = x2; by2[o] = y2;
  keys[o] = k;
}

__global__ __launch_bounds__(1024) void prep_kernel(
    const unsigned* __restrict__ keys,
    const float* __restrict__ bx1, const float* __restrict__ by1,
    const float* __restrict__ bx2, const float* __restrict__ by2,
    unsigned char* __restrict__ flags,
    float* __restrict__ cx1, float* __restrict__ cy1,
    float* __restrict__ cx2, float* __restrict__ cy2,
    float* __restrict__ car, int* __restrict__ ncand) {
  const int b = blockIdx.x;
  const int tid = threadIdx.x;
  __shared__ unsigned hist[256];
  __shared__ unsigned ssc[1024];
  __shared__ unsigned sh_prefix, sh_k;
  const unsigned* kb = keys + (size_t)b * NPAD;

  if (tid == 0) { sh_prefix = 0u; sh_k = PRE; }
  __syncthreads();

  for (int level = 0; level < 4; ++level) {
    const int shift = 24 - 8 * level;
    if (tid < 256) hist[tid] = 0u;
    __syncthreads();
    unsigned pre = sh_prefix;
    for (int i = tid; i < N_ANCHN; i += 1024) {
      unsigned k = kb[i];
      bool match = (level == 0) || ((k >> (shift + 8)) == (pre >> (shift + 8)));
      if (match) atomicAdd(&hist[(k >> shift) & 255u], 1u);
    }
    __syncthreads();
    if (tid == 0) {
      unsigned kk = sh_k, cum = 0;
      for (int d = 255; d >= 0; --d) {
        unsigned c = hist[d];
        if (cum + c >= kk) { sh_k = kk - cum; sh_prefix = pre | ((unsigned)d << shift); break; }
        cum += c;
      }
    }
    __syncthreads();
  }
  const unsigned T = sh_prefix;

  unsigned local = 0;
  for (int i = tid; i < N_ANCHN; i += 1024) local += (kb[i] > T) ? 1u : 0u;
  ssc[tid] = local;
  __syncthreads();
  for (int off = 512; off > 0; off >>= 1) {
    if (tid < off) ssc[tid] += ssc[tid + off];
    __syncthreads();
  }
  const unsigned slots = PRE - ssc[0];
  __syncthreads();

  const int SEG = (N_ANCHN + 1023) / 1024;
  const float* X1 = bx1 + (size_t)b * NPAD;
  const float* Y1 = by1 + (size_t)b * NPAD;
  const float* X2 = bx2 + (size_t)b * NPAD;
  const float* Y2 = by2 + (size_t)b * NPAD;
  unsigned char* fb = flags + (size_t)b * NPAD;

  {
    int i0 = tid * SEG, i1 = min(N_ANCHN, i0 + SEG);
    unsigned cnt = 0;
    for (int i = i0; i < i1; ++i) cnt += (kb[i] == T) ? 1u : 0u;
    ssc[tid] = cnt;
    __syncthreads();
    for (int off = 1; off < 1024; off <<= 1) {
      unsigned v = (tid >= off) ? ssc[tid - off] : 0u;
      __syncthreads();
      ssc[tid] += v;
      __syncthreads();
    }
    unsigned r = ssc[tid] - cnt;
    for (int i = i0; i < i1; ++i) {
      unsigned k = kb[i];
      bool valid = (__fsub_rn(Y2[i], Y1[i]) >= MINSZ) && (__fsub_rn(X2[i], X1[i]) >= MINSZ);
      bool tie = (k == T);
      bool cand = valid && ((k > T) || (tie && r < slots));
      if (tie) r++;
      fb[i] = cand ? (unsigned char)1 : (unsigned char)0;
    }
  }
  __syncthreads();

  {
    int j0 = tid * SEG, j1 = min(N_ANCHN, j0 + SEG);
    unsigned cnt = 0;
    for (int j = j0; j < j1; ++j) cnt += fb[N_ANCHN - 1 - j];
    ssc[tid] = cnt;
    __syncthreads();
    for (int off = 1; off < 1024; off <<= 1) {
      unsigned v = (tid >= off) ? ssc[tid - off] : 0u;
      __syncthreads();
      ssc[tid] += v;
      __syncthreads();
    }
    unsigned p = ssc[tid] - cnt;
    if (tid == 0) ncand[b] = (int)ssc[1023];
    float* CX1 = cx1 + (size_t)b * CPAD;
    float* CY1 = cy1 + (size_t)b * CPAD;
    float* CX2 = cx2 + (size_t)b * CPAD;
    float* CY2 = cy2 + (size_t)b * CPAD;
    float* CAR = car + (size_t)b * CPAD;
    for (int j = j0; j < j1; ++j) {
      int i = N_ANCHN - 1 - j;
      if (fb[i]) {
        float x1v = X1[i], y1v = Y1[i], x2v = X2[i], y2v = Y2[i];
        CX1[p] = x1v; CY1[p] = y1v; CX2[p] = x2v; CY2[p] = y2v;
        CAR[p] = __fmul_rn(__fadd_rn(__fsub_rn(x2v, x1v), 1.0f),
                           __fadd_rn(__fsub_rn(y2v, y1v), 1.0f));
        p++;
      }
    }
  }
}

__global__ __launch_bounds__(1024) void nms_kernel(
    const float* __restrict__ cx1, const float* __restrict__ cy1,
    const float* __restrict__ cx2, const float* __restrict__ cy2,
    const float* __restrict__ car, const int* __restrict__ ncand,
    float* __restrict__ out) {
  const int b = blockIdx.x;
  const int tid = threadIdx.x;
  __shared__ float sx1[POST], sy1[POST], sx2[POST], sy2[POST], sar[POST];
  __shared__ int Lbuf[1024];
  __shared__ int wcount[16];
  __shared__ int sh_sc;

  const float* CX1 = cx1 + (size_t)b * CPAD;
  const float* CY1 = cy1 + (size_t)b * CPAD;
  const float* CX2 = cx2 + (size_t)b * CPAD;
  const float* CY2 = cy2 + (size_t)b * CPAD;
  const float* CAR = car + (size_t)b * CPAD;
  float* roib = out + (size_t)b * POST * 4;
  float* maskb = out + (size_t)BATCH * POST * 4 + (size_t)b * POST;

  const int n = ncand[b];
  if (tid == 0) sh_sc = 0;
  __syncthreads();
  const int lane = tid & 63;
  const int w = tid >> 6;

  for (int base = 0; base < n; base += 1024) {
    const int c = base + tid;
    bool pass = (c < n);
    float px1 = 0, py1 = 0, px2 = 0, py2 = 0, par = 0;
    if (pass) { px1 = CX1[c]; py1 = CY1[c]; px2 = CX2[c]; py2 = CY2[c]; par = CAR[c]; }
    const int sc0 = sh_sc;

    if (pass) {
      for (int k = 0; k < sc0; ++k) {
        float ovr = iou_ref(sx1[k], sy1[k], sx2[k], sy2[k], sar[k], px1, py1, px2, py2, par);
        if (ovr > NMS_T) { pass = false; break; }
      }
    }

    unsigned long long bal = __ballot(pass);
    if (lane == 0) wcount[w] = (int)__popcll(bal);
    __syncthreads();
    int off = 0;
    for (int q = 0; q < 16; ++q) off += (q < w) ? wcount[q] : 0;
    if (pass) Lbuf[off + (int)__popcll(bal & ((1ULL << lane) - 1ULL))] = c;
    __syncthreads();

    if (tid < 64) {
      int total = 0;
      for (int q = 0; q < 16; ++q) total += wcount[q];
      int sc = sc0;
      for (int g = 0; g < total && sc < POST; g += 64) {
        int idx = (g + lane < total) ? Lbuf[g + lane] : -1;
        float qx1 = 0, qy1 = 0, qx2 = 0, qy2 = 0, qar = 0;
        bool al = (idx >= 0);
        if (al) { qx1 = CX1[idx]; qy1 = CY1[idx]; qx2 = CX2[idx]; qy2 = CY2[idx]; qar = CAR[idx]; }
        for (int k = sc0; k < sc && al; ++k) {
          float ovr = iou_ref(sx1[k], sy1[k], sx2[k], sy2[k], sar[k], qx1, qy1, qx2, qy2, qar);
          if (ovr > NMS_T) al = false;
        }
        unsigned long long alive = __ballot(al);
        while (alive && sc < POST) {
          int j = (int)__builtin_ctzll(alive);
          float jx1 = __shfl(qx1, j), jy1 = __shfl(qy1, j);
          float jx2 = __shfl(qx2, j), jy2 = __shfl(qy2, j), jar = __shfl(qar, j);
          float ovr = iou_ref(jx1, jy1, jx2, jy2, jar, qx1, qy1, qx2, qy2, qar);
          unsigned long long killm = __ballot(ovr > NMS_T);
          alive &= ~killm;
          alive &= ~(1ULL << j);
          if (lane == 0) {
            sx1[sc] = jx1; sy1[sc] = jy1; sx2[sc] = jx2; sy2[sc] = jy2; sar[sc] = jar;
            roib[(size_t)sc * 4 + 0] = jx1;
            roib[(size_t)sc * 4 + 1] = jy1;
            roib[(size_t)sc * 4 + 2] = jx2;
            roib[(size_t)sc * 4 + 3] = jy2;
          }
          sc++;
        }
      }
      if (lane == 0) sh_sc = sc;
    }
    __syncthreads();
    if (sh_sc >= POST) break;
  }
  __syncthreads();

  const int sc = sh_sc;
  for (int t = tid; t < POST; t += 1024) {
    if (t >= sc) {
      roib[(size_t)t * 4 + 0] = 0.f; roib[(size_t)t * 4 + 1] = 0.f;
      roib[(size_t)t * 4 + 2] = 0.f; roib[(size_t)t * 4 + 3] = 0.f;
    }
    maskb[t] = (t < sc) ? 1.0f : 0.0f;
  }
}

extern "C" void kernel_launch(void* const* d_in, const int* in_sizes, int n_in,
                              void* d_out, int out_size, void* d_ws, size_t ws_size,
                              hipStream_t stream) {
  const float* anchors = (const float*)d_in[0];
  const float* cls = (const float*)d_in[1];
  const float* bbox = (const float*)d_in[2];
  float* out = (float*)d_out;
  char* ws = (char*)d_ws;

  // ---- persistent region ----
  size_t o = 0;
  float* cx1 = (float*)(ws + o); o += (size_t)BATCH * CPAD * 4;
  float* cy1 = (float*)(ws + o); o += (size_t)BATCH * CPAD * 4;
  float* cx2 = (float*)(ws + o); o += (size_t)BATCH * CPAD * 4;
  float* cy2 = (float*)(ws + o); o += (size_t)BATCH * CPAD * 4;
  float* car = (float*)(ws + o); o += (size_t)BATCH * CPAD * 4;
  int* ncand = (int*)(ws + o); o += 256;
  u64* diag = (u64*)(ws + o); o += (size_t)BATCH * WPB * 64 * 8;
  unsigned* rowcnt = (unsigned*)(ws + o); o += (size_t)BATCH * CPAD * 4;
  float* wminx1 = (float*)(ws + o); o += (size_t)BATCH * WPB * 4;
  float* wmaxx2 = (float*)(ws + o); o += (size_t)BATCH * WPB * 4;
  float* sx1 = (float*)(ws + o); o += (size_t)BATCH * CPAD * 4;
  float* sy1 = (float*)(ws + o); o += (size_t)BATCH * CPAD * 4;
  float* sx2 = (float*)(ws + o); o += (size_t)BATCH * CPAD * 4;
  float* sy2 = (float*)(ws + o); o += (size_t)BATCH * CPAD * 4;
  float* sar = (float*)(ws + o); o += (size_t)BATCH * CPAD * 4;
  int* sperm = (int*)(ws + o); o += (size_t)BATCH * CPAD * 4;
  size_t overlay = o;     // decode region and rows_t share this space
  unsigned* keys = (unsigned*)(ws + overlay);
  float* bx1 = (float*)(ws + overlay + (size_t)BATCH * NPAD * 4 * 1);
  float* by1 = (float*)(ws + overlay + (size_t)BATCH * NPAD * 4 * 2);
  float* bx2 = (float*)(ws + overlay + (size_t)BATCH * NPAD * 4 * 3);
  float* by2 = (float*)(ws + overlay + (size_t)BATCH * NPAD * 4 * 4);
  size_t decode_bytes = (size_t)BATCH * NPAD * 4 * 5;
  unsigned short* rows_t = (unsigned short*)(ws + overlay);  // build writes AFTER prepsort reads

  int L = 0;
  for (int Ltry = 32; Ltry >= 16; Ltry -= 16) {
    size_t rows_bytes = (size_t)BATCH * Ltry * CPAD * 2;
    size_t need = overlay + (decode_bytes > rows_bytes ? decode_bytes : rows_bytes);
    if (ws_size >= need) { L = Ltry; break; }
  }

  if (L > 0) {
    dim3 dgrid((N_ANCHN + 255) / 256 + 1, BATCH);   // last x-block zeroes diag/rowcnt
    decode_kernel<<<dgrid, 256, 0, stream>>>(anchors, cls, bbox, bx1, by1, bx2, by2,
                                             keys, diag, rowcnt);
    prepsort_kernel<<<BATCH, 1024, 0, stream>>>(keys, bx1, by1, bx2, by2,
                                                cx1, cy1, cx2, cy2, car, ncand,
                                                sx1, sy1, sx2, sy2, sar, sperm,
                                                wminx1, wmaxx2);
    build_kernel<<<dim3(WPB, (WPB + 3) / 4, BATCH), 64, 0, stream>>>(
        sx1, sy1, sx2, sy2, sar, sperm, ncand, wminx1, wmaxx2,
        diag, rowcnt, rows_t, L);
    scan_kernel<<<BATCH, 64, 0, stream>>>(cx1, cy1, cx2, cy2, car, ncand,
                                          diag, rowcnt, rows_t, L, out);
  } else {
    // tiny-ws fallback: round-1 layout + kernels
    size_t f = 0;
    unsigned* fkeys = (unsigned*)(ws + f); f += (size_t)BATCH * NPAD * 4;
    float* fbx1 = (float*)(ws + f); f += (size_t)BATCH * NPAD * 4;
    float* fby1 = (float*)(ws + f); f += (size_t)BATCH * NPAD * 4;
    float* fbx2 = (float*)(ws + f); f += (size_t)BATCH * NPAD * 4;
    float* fby2 = (float*)(ws + f); f += (size_t)BATCH * NPAD * 4;
    float* fcx1 = (float*)(ws + f); f += (size_t)BATCH * CPAD * 4;
    float* fcy1 = (float*)(ws + f); f += (size_t)BATCH * CPAD * 4;
    float* fcx2 = (float*)(ws + f); f += (size_t)BATCH * CPAD * 4;
    float* fcy2 = (float*)(ws + f); f += (size_t)BATCH * CPAD * 4;
    float* fcar = (float*)(ws + f); f += (size_t)BATCH * CPAD * 4;
    unsigned char* fflags = (unsigned char*)(ws + f); f += (size_t)BATCH * NPAD;
    int* fncand = (int*)(ws + f); f += 256;

    dim3 dgrid((N_ANCHN + 255) / 256, BATCH);
    decode_fb_kernel<<<dgrid, 256, 0, stream>>>(anchors, cls, bbox, fbx1, fby1, fbx2, fby2, fkeys);
    prep_kernel<<<BATCH, 1024, 0, stream>>>(fkeys, fbx1, fby1, fbx2, fby2, fflags,
                                            fcx1, fcy1, fcx2, fcy2, fcar, fncand);
    nms_kernel<<<BATCH, 1024, 0, stream>>>(fcx1, fcy1, fcx2, fcy2, fcar, fncand, out);
  }
}

// Round 7
// 529.688 us; speedup vs baseline: 1.2176x; 1.0260x over previous
//
#include <hip/hip_runtime.h>
#include <math.h>

#define N_ANCHN 18675
#define NPAD    18688
#define BATCH   16
#define PRE     12000
#define CPAD    12032
#define WPB     188      // CPAD/64 words per row
#define POST    2000
#define NMS_T   0.7f
#define IMGX    1333.0f
#define IMGY    402.0f
#define MINSZ   16.0f
#define NBUCK   256
#define KINV    0x007FFFFFu   // key_of(-inf)
#define MLCAP   12288

typedef unsigned long long u64;

__device__ __forceinline__ unsigned key_of(float f) {
  unsigned u = __float_as_uint(f);
  return (u & 0x80000000u) ? ~u : (u | 0x80000000u);
}

// Reference-exact IoU: inter/(a_area + b_area - inter), +1 box convention, no FMA.
__device__ __forceinline__ float iou_ref(float ax1, float ay1, float ax2, float ay2, float aar,
                                         float bx1, float by1, float bx2, float by2, float bar) {
  float xx1 = fmaxf(ax1, bx1);
  float yy1 = fmaxf(ay1, by1);
  float xx2 = fminf(ax2, bx2);
  float yy2 = fminf(ay2, by2);
  float iw = fmaxf(0.0f, __fadd_rn(__fsub_rn(xx2, xx1), 1.0f));
  float ih = fmaxf(0.0f, __fadd_rn(__fsub_rn(yy2, yy1), 1.0f));
  float inter = __fmul_rn(iw, ih);
  return __fdiv_rn(inter, __fsub_rn(__fadd_rn(aar, bar), inter));
}

// Decision-identical to (iou_ref > 0.7): band bounds 0.395/0.43 vs exact 0.41176
// leave ~4% slack against <=1e-6 float rounding; middle band recomputes ref-exact.
__device__ __forceinline__ bool hit_test(float ix1, float iy1, float ix2, float iy2, float iar,
                                         float jx1, float jy1, float jx2, float jy2, float jar) {
  float xx1 = fmaxf(ix1, jx1);
  float yy1 = fmaxf(iy1, jy1);
  float xx2 = fminf(ix2, jx2);
  float yy2 = fminf(iy2, jy2);
  float iw = fmaxf(0.0f, __fadd_rn(__fsub_rn(xx2, xx1), 1.0f));
  float ih = fmaxf(0.0f, __fadd_rn(__fsub_rn(yy2, yy1), 1.0f));
  float inter = __fmul_rn(iw, ih);
  float S = __fadd_rn(iar, jar);
  if (inter >= __fmul_rn(0.43f, S)) return true;
  if (inter <= __fmul_rn(0.395f, S)) return false;
  return __fdiv_rn(inter, __fsub_rn(S, inter)) > NMS_T;
}

// Same-word pairs stored TRANSPOSED — diagb[word*64 + lo] bit hi means
// "lo kills hi" (kills-BY-lo mask). Lets scan's greedy chain fetch the kill
// mask of a selected box with 2 readlanes instead of a per-iteration ballot.
__device__ __forceinline__ void emit_hit(int lo, int hi, u64* diagb, unsigned* rcb,
                                         unsigned short* rtb, int L) {
  if ((hi >> 6) == (lo >> 6)) {
    atomicOr(&diagb[(size_t)(lo >> 6) * 64 + (lo & 63)], 1ull << (hi & 63));
  } else {
    unsigned slot = atomicAdd(&rcb[lo], 1u);
    if ((int)slot < L) rtb[(size_t)lo * L + slot] = (unsigned short)hi;
  }
}

__device__ __forceinline__ void decode_one(
    const float* __restrict__ anchors, const float* __restrict__ cls,
    const float* __restrict__ bbox, int b, int i,
    float& x1, float& y1, float& x2, float& y2, unsigned& key) {
  float4 A = *(const float4*)(anchors + (size_t)i * 4);
  float ah = __fsub_rn(A.w, A.y);
  float aw = __fsub_rn(A.z, A.x);
  float acy = __fadd_rn(A.y, __fmul_rn(0.5f, ah));
  float acx = __fadd_rn(A.x, __fmul_rn(0.5f, aw));

  float4 P = *(const float4*)(bbox + ((size_t)b * N_ANCHN + i) * 4);
  float dx = P.x, dy = P.y, dw = P.z, dh = P.w;

  float cy = __fadd_rn(__fmul_rn(dy, ah), acy);
  float cx = __fadd_rn(__fmul_rn(dx, aw), acx);
  float eh = (float)exp((double)dh);
  float ew = (float)exp((double)dw);
  float h = __fmul_rn(eh, ah);
  float w = __fmul_rn(ew, aw);

  x1 = fminf(fmaxf(__fsub_rn(cx, __fmul_rn(0.5f, w)), 0.0f), IMGX);
  y1 = fminf(fmaxf(__fsub_rn(cy, __fmul_rn(0.5f, h)), 0.0f), IMGY);
  x2 = fminf(fmaxf(__fadd_rn(cx, __fmul_rn(0.5f, w)), 0.0f), IMGX);
  y2 = fminf(fmaxf(__fadd_rn(cy, __fmul_rn(0.5f, h)), 0.0f), IMGY);

  bool valid = (__fsub_rn(y2, y1) >= MINSZ) && (__fsub_rn(x2, x1) >= MINSZ);
  float s = valid ? cls[(size_t)b * (2 * N_ANCHN) + 2 * i + 1] : -INFINITY;
  key = key_of(s);
}

// ---------------- Kernel 1: full-grid decode (+ zeroing column) ----------------
__global__ __launch_bounds__(256) void decode_kernel(
    const float* __restrict__ anchors, const float* __restrict__ cls,
    const float* __restrict__ bbox,
    float* __restrict__ bx1, float* __restrict__ by1,
    float* __restrict__ bx2, float* __restrict__ by2,
    unsigned* __restrict__ keys,
    u64* __restrict__ diag, unsigned* __restrict__ rowcnt) {
  const int bx = blockIdx.x;
  const int b = blockIdx.y;
  if (bx == gridDim.x - 1) {
    u64* dz = diag + (size_t)b * WPB * 64;
    for (int i = threadIdx.x; i < WPB * 64; i += 256) dz[i] = 0ull;
    unsigned* rz = rowcnt + (size_t)b * CPAD;
    for (int i = threadIdx.x; i < CPAD; i += 256) rz[i] = 0u;
    return;
  }
  int i = bx * 256 + threadIdx.x;
  if (i >= N_ANCHN) return;
  float x1, y1, x2, y2; unsigned k;
  decode_one(anchors, cls, bbox, b, i, x1, y1, x2, y2, k);
  size_t o = (size_t)b * NPAD + i;
  bx1[o] = x1; by1[o] = y1; bx2[o] = x2; by2[o] = y2;
  keys[o] = k;
}

// ---------------- Kernel 2: prep (radix-select + compaction) + x-sort ----------------
__global__ __launch_bounds__(1024) void prepsort_kernel(
    const unsigned* __restrict__ keys,
    const float* __restrict__ bx1, const float* __restrict__ by1,
    const float* __restrict__ bx2, const float* __restrict__ by2,
    float* __restrict__ cx1, float* __restrict__ cy1,
    float* __restrict__ cx2, float* __restrict__ cy2,
    float* __restrict__ car, int* __restrict__ ncand,
    float* __restrict__ sx1, float* __restrict__ sy1,
    float* __restrict__ sx2, float* __restrict__ sy2,
    float* __restrict__ sar, int* __restrict__ sperm,
    float* __restrict__ wminx1, float* __restrict__ wmaxx2) {
  const int b = blockIdx.x;
  const int tid = threadIdx.x;
  const int lane = tid & 63;
  const int wv = tid >> 6;
  __shared__ unsigned hist[16][256];
  __shared__ unsigned mh[256];
  __shared__ unsigned wsum[16];
  __shared__ unsigned bh[NBUCK];
  __shared__ unsigned boff[NBUCK];
  __shared__ unsigned char fb[NPAD];
  __shared__ unsigned short mlist[MLCAP];
  __shared__ unsigned sh_prefix, sh_k, sh_n, sh_mcount;
  const unsigned* kb = keys + (size_t)b * NPAD;

  if (tid == 0) { sh_prefix = 0u; sh_k = PRE; sh_mcount = 0u; }
  __syncthreads();

  // ---- radix level 0 (full scan) ----
  {
    for (int idx = tid; idx < 16 * 256; idx += 1024) ((unsigned*)hist)[idx] = 0u;
    __syncthreads();
    for (int i = tid; i < N_ANCHN; i += 1024)
      atomicAdd(&hist[wv][kb[i] >> 24], 1u);
    __syncthreads();
    if (tid < 256) {
      unsigned s = 0;
#pragma unroll
      for (int q = 0; q < 16; ++q) s += hist[q][tid];
      mh[tid] = s;
    }
    __syncthreads();
    if (tid == 0) {
      unsigned kk = sh_k, cum = 0;
      for (int d = 255; d >= 0; --d) {
        unsigned c = mh[d];
        if (cum + c >= kk) { sh_k = kk - cum; sh_prefix = (unsigned)d << 24; break; }
        cum += c;
      }
    }
    __syncthreads();
  }

  // ---- compact indices matching top byte (narrows levels 1-3) ----
  {
    unsigned b0 = sh_prefix >> 24;
    for (int i = tid; i < N_ANCHN; i += 1024) {
      if ((kb[i] >> 24) == b0) {
        unsigned p = atomicAdd(&sh_mcount, 1u);
        if (p < MLCAP) mlist[p] = (unsigned short)i;
      }
    }
  }
  __syncthreads();
  const bool useList = (sh_mcount <= (unsigned)MLCAP);
  const unsigned mcount = min(sh_mcount, (unsigned)MLCAP);

  // ---- radix levels 1-3 (list-narrowed; exact fallback) ----
  for (int level = 1; level < 4; ++level) {
    const int shift = 24 - 8 * level;
    for (int idx = tid; idx < 16 * 256; idx += 1024) ((unsigned*)hist)[idx] = 0u;
    __syncthreads();
    unsigned pre = sh_prefix;
    if (useList) {
      for (int idx = tid; idx < (int)mcount; idx += 1024) {
        unsigned k = kb[mlist[idx]];
        if ((k >> (shift + 8)) == (pre >> (shift + 8)))
          atomicAdd(&hist[wv][(k >> shift) & 255u], 1u);
      }
    } else {
      for (int i = tid; i < N_ANCHN; i += 1024) {
        unsigned k = kb[i];
        if ((k >> (shift + 8)) == (pre >> (shift + 8)))
          atomicAdd(&hist[wv][(k >> shift) & 255u], 1u);
      }
    }
    __syncthreads();
    if (tid < 256) {
      unsigned s = 0;
#pragma unroll
      for (int q = 0; q < 16; ++q) s += hist[q][tid];
      mh[tid] = s;
    }
    __syncthreads();
    if (tid == 0) {
      unsigned kk = sh_k, cum = 0;
      for (int d = 255; d >= 0; --d) {
        unsigned c = mh[d];
        if (cum + c >= kk) { sh_k = kk - cum; sh_prefix = pre | ((unsigned)d << shift); break; }
        cum += c;
      }
    }
    __syncthreads();
  }
  const unsigned T = sh_prefix;
  // radix-select invariant: after the last level, sh_k = PRE - count(keys > T) = tie slots
  const unsigned slots = sh_k;

  const int SEG = (N_ANCHN + 1023) / 1024;

  // ---- flags with stable tie-rank (keys only; wave-scan for tie prefix) ----
  {
    int i0 = tid * SEG, i1 = min(N_ANCHN, i0 + SEG);
    unsigned cnt = 0;
    for (int i = i0; i < i1; ++i) cnt += (kb[i] == T) ? 1u : 0u;
    unsigned v = cnt;
#pragma unroll
    for (int d = 1; d < 64; d <<= 1) {
      unsigned y = __shfl_up(v, d, 64);
      if (lane >= d) v += y;
    }
    if (lane == 63) wsum[wv] = v;
    __syncthreads();
    if (tid == 0) {
      unsigned acc = 0;
#pragma unroll
      for (int q = 0; q < 16; ++q) { unsigned t = wsum[q]; wsum[q] = acc; acc += t; }
    }
    __syncthreads();
    unsigned r = wsum[wv] + v - cnt;   // exclusive tie rank base
    for (int i = i0; i < i1; ++i) {
      unsigned k = kb[i];
      bool tie = (k == T);
      bool cand = (k > T) || (tie && T > KINV && r < slots);
      if (tie) r++;
      fb[i] = cand ? (unsigned char)1 : (unsigned char)0;
    }
  }
  __syncthreads();

  // ---- ordered compaction: descending anchor index (wave-scan prefix) ----
  const float* X1 = bx1 + (size_t)b * NPAD;
  const float* Y1 = by1 + (size_t)b * NPAD;
  const float* X2 = bx2 + (size_t)b * NPAD;
  const float* Y2 = by2 + (size_t)b * NPAD;
  {
    int j0 = tid * SEG, j1 = min(N_ANCHN, j0 + SEG);
    unsigned cnt = 0;
    for (int j = j0; j < j1; ++j) cnt += fb[N_ANCHN - 1 - j];
    unsigned v = cnt;
#pragma unroll
    for (int d = 1; d < 64; d <<= 1) {
      unsigned y = __shfl_up(v, d, 64);
      if (lane >= d) v += y;
    }
    if (lane == 63) wsum[wv] = v;
    __syncthreads();
    if (tid == 0) {
      unsigned acc = 0;
#pragma unroll
      for (int q = 0; q < 16; ++q) { unsigned t = wsum[q]; wsum[q] = acc; acc += t; }
      sh_n = acc;
    }
    __syncthreads();
    unsigned p = wsum[wv] + v - cnt;
    if (tid == 0) ncand[b] = (int)sh_n;
    float* CX1 = cx1 + (size_t)b * CPAD;
    float* CY1 = cy1 + (size_t)b * CPAD;
    float* CX2 = cx2 + (size_t)b * CPAD;
    float* CY2 = cy2 + (size_t)b * CPAD;
    float* CAR = car + (size_t)b * CPAD;
    for (int j = j0; j < j1; ++j) {
      int i = N_ANCHN - 1 - j;
      if (fb[i]) {
        float x1v = X1[i], y1v = Y1[i], x2v = X2[i], y2v = Y2[i];
        CX1[p] = x1v; CY1[p] = y1v; CX2[p] = x2v; CY2[p] = y2v;
        CAR[p] = __fmul_rn(__fadd_rn(__fsub_rn(x2v, x1v), 1.0f),
                           __fadd_rn(__fsub_rn(y2v, y1v), 1.0f));
        p++;
      }
    }
  }
  __syncthreads();
  const int n = (int)sh_n;

  // ---- 256-bucket x1 sort + per-word aggregates (R7-proven layout) ----
  const float scale = (float)NBUCK / 1334.0f;
  const float* CX1 = cx1 + (size_t)b * CPAD;
  const float* CY1 = cy1 + (size_t)b * CPAD;
  const float* CX2 = cx2 + (size_t)b * CPAD;
  const float* CY2 = cy2 + (size_t)b * CPAD;
  const float* CAR = car + (size_t)b * CPAD;
  float* SX1 = sx1 + (size_t)b * CPAD;
  float* SY1 = sy1 + (size_t)b * CPAD;
  float* SX2 = sx2 + (size_t)b * CPAD;
  float* SY2 = sy2 + (size_t)b * CPAD;
  float* SAR = sar + (size_t)b * CPAD;
  int* SP = sperm + (size_t)b * CPAD;

  if (tid < NBUCK) bh[tid] = 0u;
  __syncthreads();
  for (int i = tid; i < n; i += 1024) {
    int q = (int)(CX1[i] * scale);
    q = q < 0 ? 0 : (q > NBUCK - 1 ? NBUCK - 1 : q);
    atomicAdd(&bh[q], 1u);
  }
  __syncthreads();
  if (tid < 64) {
    unsigned carry = 0;
    for (int c = 0; c < 4; ++c) {
      unsigned own = bh[c * 64 + tid];
      unsigned v = own;
      for (int d = 1; d < 64; d <<= 1) {
        unsigned y = __shfl_up(v, d, 64);
        if (tid >= d) v += y;
      }
      boff[c * 64 + tid] = carry + v - own;
      carry += __shfl(v, 63, 64);
    }
  }
  __syncthreads();
  for (int i = tid; i < n; i += 1024) {
    float x1v = CX1[i];
    int q = (int)(x1v * scale);
    q = q < 0 ? 0 : (q > NBUCK - 1 ? NBUCK - 1 : q);
    unsigned p = atomicAdd(&boff[q], 1u);
    SX1[p] = x1v; SY1[p] = CY1[i]; SX2[p] = CX2[i]; SY2[p] = CY2[i];
    SAR[p] = CAR[i]; SP[p] = i;
  }
  for (int i = n + tid; i < CPAD; i += 1024) {
    SX1[i] = 1e30f; SY1[i] = 1e30f; SX2[i] = -1e30f; SY2[i] = -1e30f;
    SAR[i] = 1.0f; SP[i] = 0;
  }
  __syncthreads();
  // wave-parallel per-word aggregates: wave wv handles words wv, wv+16, ...
  for (int w = wv; w < WPB; w += 16) {
    float mn = SX1[64 * w + lane];
    float mx = SX2[64 * w + lane];
#pragma unroll
    for (int d = 32; d > 0; d >>= 1) {
      mn = fminf(mn, __shfl_xor(mn, d, 64));
      mx = fmaxf(mx, __shfl_xor(mx, d, 64));
    }
    if (lane == 0) {
      wminx1[(size_t)b * WPB + w] = mn;
      wmaxx2[(size_t)b * WPB + w] = mx;
    }
  }
}

// ---------------- Kernel 3: transposed banded build, 4-wave blocks ----------------
// R7: block = (row word R, 16-word column span G0). Wave q owns the 4-word
// group w0 = 16*G0 + 4q; each lane holds those 4 columns in registers. All 4
// waves share one LDS row stage (barrier once). Per-(R,word) band test and
// dedup are IDENTICAL to R6 (same vX conditions, same emits) — only the block
// decomposition changes, so diag/rows_t are bit-identical. New:
//  * block-level monotone prune (WMN is monotone up to one x-bucket width
//    5.211px -> conservative +5.25 margin) kills dead blocks before staging;
//  * dd-specialized hot loop for waves with all words > R (no lane>k checks).
// Rationale: 141k 1-wave blocks (120k instant-exit) caused dispatch churn
// (Occupancy 55%); 36k 4-wave blocks keep CUs full.
__global__ __launch_bounds__(256) void build_kernel(
    const float* __restrict__ sx1, const float* __restrict__ sy1,
    const float* __restrict__ sx2, const float* __restrict__ sy2,
    const float* __restrict__ sar, const int* __restrict__ sperm,
    const int* __restrict__ ncand,
    const float* __restrict__ wminx1, const float* __restrict__ wmaxx2,
    u64* __restrict__ diagT, unsigned* __restrict__ rowcnt,
    unsigned short* __restrict__ rows_t, int L) {
  const int R = blockIdx.x, G0 = blockIdx.y, b = blockIdx.z;
  const int n = ncand[b];
  if (64 * R >= n) return;
  if (16 * G0 + 15 < R) return;          // whole span below row word
  const float* WMN = wminx1 + (size_t)b * WPB;
  const float rlim = __fadd_rn(wmaxx2[(size_t)b * WPB + R], 2.0f);
  {
    // block prune: words >= wlo have WMN > WMN[wlo] - 5.211 (bucket-width
    // quasi-monotonicity of the 256-bucket x1 sort); conservative margin.
    const int wlo = max(16 * G0, R);     // <= 187 (G0<=11, R<WPB)
    if (WMN[wlo] > __fadd_rn(rlim, 5.25f)) return;
  }

  const float* SX1 = sx1 + (size_t)b * CPAD;
  const float* SY1 = sy1 + (size_t)b * CPAD;
  const float* SX2 = sx2 + (size_t)b * CPAD;
  const float* SY2 = sy2 + (size_t)b * CPAD;
  const float* SAR = sar + (size_t)b * CPAD;
  const int* SP = sperm + (size_t)b * CPAD;

  const int t = threadIdx.x, lane = t & 63, q = t >> 6;

  // shared row stage for all 4 waves: box (float4) + packed {area, sperm}
  __shared__ float4 rbv[64];
  __shared__ float2 ras[64];
  if (t < 64) {
    int i = 64 * R + t;
    rbv[t] = make_float4(SX1[i], SY1[i], SX2[i], SY2[i]);
  } else if (t < 128) {
    int i = 64 * R + (t - 64);
    ras[t - 64] = make_float2(SAR[i], __int_as_float(SP[i]));
  }
  const float rx2own = SX2[64 * R + lane];   // direct load (no LDS dependency)
  __syncthreads();

  const int w0 = 16 * G0 + 4 * q;
  const float wmn0 = WMN[min(w0 + 0, WPB - 1)];
  const float wmn1 = WMN[min(w0 + 1, WPB - 1)];
  const float wmn2 = WMN[min(w0 + 2, WPB - 1)];
  const float wmn3 = WMN[min(w0 + 3, WPB - 1)];
  // pad words (>= n) have wmn=1e30 > rlim -> auto-invalid
  const bool v0 = (w0 + 0 < WPB) && (w0 + 0 >= R) && (wmn0 <= rlim);
  const bool v1 = (w0 + 1 < WPB) && (w0 + 1 >= R) && (wmn1 <= rlim);
  const bool v2 = (w0 + 2 < WPB) && (w0 + 2 >= R) && (wmn2 <= rlim);
  const bool v3 = (w0 + 3 < WPB) && (w0 + 3 >= R) && (wmn3 <= rlim);
  if (!(v0 | v1 | v2 | v3)) return;      // no more barriers below: safe

  // this wave's 4 columns per lane, in registers (loads skipped for invalid words)
  float c0x1 = 1e30f, c0y1 = 0.f, c0x2 = 0.f, c0y2 = 0.f, c0ar = 1.f; int c0sp = 0;
  float c1x1 = 1e30f, c1y1 = 0.f, c1x2 = 0.f, c1y2 = 0.f, c1ar = 1.f; int c1sp = 0;
  float c2x1 = 1e30f, c2y1 = 0.f, c2x2 = 0.f, c2y2 = 0.f, c2ar = 1.f; int c2sp = 0;
  float c3x1 = 1e30f, c3y1 = 0.f, c3x2 = 0.f, c3y2 = 0.f, c3ar = 1.f; int c3sp = 0;
  if (v0) { int j = 64 * (w0 + 0) + lane;
    c0x1 = SX1[j]; c0y1 = SY1[j]; c0x2 = SX2[j]; c0y2 = SY2[j]; c0ar = SAR[j]; c0sp = SP[j]; }
  if (v1) { int j = 64 * (w0 + 1) + lane;
    c1x1 = SX1[j]; c1y1 = SY1[j]; c1x2 = SX2[j]; c1y2 = SY2[j]; c1ar = SAR[j]; c1sp = SP[j]; }
  if (v2) { int j = 64 * (w0 + 2) + lane;
    c2x1 = SX1[j]; c2y1 = SY1[j]; c2x2 = SX2[j]; c2y2 = SY2[j]; c2ar = SAR[j]; c2sp = SP[j]; }
  if (v3) { int j = 64 * (w0 + 3) + lane;
    c3x1 = SX1[j]; c3y1 = SY1[j]; c3x2 = SX2[j]; c3y2 = SY2[j]; c3ar = SAR[j]; c3sp = SP[j]; }

  // active-row mask from the loosest (lowest-wmn) valid word
  const float wmnlo = v0 ? wmn0 : (v1 ? wmn1 : (v2 ? wmn2 : wmn3));
  u64 a = __ballot(rx2own >= __fsub_rn(wmnlo, 2.0f));
  if (!a) return;

  const float wmn0m2 = __fsub_rn(wmn0, 2.0f);
  const float wmn1m2 = __fsub_rn(wmn1, 2.0f);
  const float wmn2m2 = __fsub_rn(wmn2, 2.0f);
  const float wmn3m2 = __fsub_rn(wmn3, 2.0f);

  u64* diagb = diagT + (size_t)b * WPB * 64;
  unsigned* rcb = rowcnt + (size_t)b * CPAD;
  unsigned short* rtb = rows_t + (size_t)b * L * CPAD;

  const bool diagIn = (w0 <= R) & (R <= w0 + 3);
  if (!diagIn) {
    // HOT PATH: all valid words > R -> dedup always true, no lane>k checks.
    int k = (int)__builtin_ctzll(a);
    float4 RB = rbv[k];
    float2 AS = ras[k];
    while (true) {
      a &= a - 1;
      const int kn = a ? (int)__builtin_ctzll(a) : 0;
      const float4 RBn = rbv[kn];      // prefetch next row
      const float2 ASn = ras[kn];
      const float rx2k = RB.z;
      const float rark = AS.x;
      const int rsp = __float_as_int(AS.y);
      if (v0 && rx2k >= wmn0m2 &&
          hit_test(RB.x, RB.y, RB.z, RB.w, rark, c0x1, c0y1, c0x2, c0y2, c0ar))
        emit_hit(min(rsp, c0sp), max(rsp, c0sp), diagb, rcb, rtb, L);
      if (v1 && rx2k >= wmn1m2 &&
          hit_test(RB.x, RB.y, RB.z, RB.w, rark, c1x1, c1y1, c1x2, c1y2, c1ar))
        emit_hit(min(rsp, c1sp), max(rsp, c1sp), diagb, rcb, rtb, L);
      if (v2 && rx2k >= wmn2m2 &&
          hit_test(RB.x, RB.y, RB.z, RB.w, rark, c2x1, c2y1, c2x2, c2y2, c2ar))
        emit_hit(min(rsp, c2sp), max(rsp, c2sp), diagb, rcb, rtb, L);
      if (v3 && rx2k >= wmn3m2 &&
          hit_test(RB.x, RB.y, RB.z, RB.w, rark, c3x1, c3y1, c3x2, c3y2, c3ar))
        emit_hit(min(rsp, c3sp), max(rsp, c3sp), diagb, rcb, rtb, L);
      if (!a) break;
      RB = RBn; AS = ASn;
    }
  } else {
    // DIAGONAL PATH: word == R possible -> per-pair lane>k dedup (R6 loop).
    const bool g0 = (w0 + 0 > R), e0 = (w0 + 0 == R);
    const bool g1 = (w0 + 1 > R), e1 = (w0 + 1 == R);
    const bool g2 = (w0 + 2 > R), e2 = (w0 + 2 == R);
    const bool g3 = (w0 + 3 > R), e3 = (w0 + 3 == R);
    int k = (int)__builtin_ctzll(a);
    float4 RB = rbv[k];
    float2 AS = ras[k];
    while (true) {
      a &= a - 1;
      const int kn = a ? (int)__builtin_ctzll(a) : 0;
      const float4 RBn = rbv[kn];
      const float2 ASn = ras[kn];
      const float rx2k = RB.z;
      const float rark = AS.x;
      const int rsp = __float_as_int(AS.y);
      if (v0 && rx2k >= wmn0m2) {
        bool dd = g0 | (e0 & (lane > k));
        if (dd && hit_test(RB.x, RB.y, RB.z, RB.w, rark, c0x1, c0y1, c0x2, c0y2, c0ar))
          emit_hit(min(rsp, c0sp), max(rsp, c0sp), diagb, rcb, rtb, L);
      }
      if (v1 && rx2k >= wmn1m2) {
        bool dd = g1 | (e1 & (lane > k));
        if (dd && hit_test(RB.x, RB.y, RB.z, RB.w, rark, c1x1, c1y1, c1x2, c1y2, c1ar))
          emit_hit(min(rsp, c1sp), max(rsp, c1sp), diagb, rcb, rtb, L);
      }
      if (v2 && rx2k >= wmn2m2) {
        bool dd = g2 | (e2 & (lane > k));
        if (dd && hit_test(RB.x, RB.y, RB.z, RB.w, rark, c2x1, c2y1, c2x2, c2y2, c2ar))
          emit_hit(min(rsp, c2sp), max(rsp, c2sp), diagb, rcb, rtb, L);
      }
      if (v3 && rx2k >= wmn3m2) {
        bool dd = g3 | (e3 & (lane > k));
        if (dd && hit_test(RB.x, RB.y, RB.z, RB.w, rark, c3x1, c3y1, c3x2, c3y2, c3ar))
          emit_hit(min(rsp, c3sp), max(rsp, c3sp), diagb, rcb, rtb, L);
      }
      if (!a) break;
      k = kn; RB = RBn; AS = ASn;
    }
  }
}

// ---------------- Kernel 4: ballot-free scalar-chain greedy NMS ----------------
// kw is kills-BY-lane (transposed diag). The greedy chain per word is pure
// uniform arithmetic: j = ctz(act); kj = readlane(kw, j); act &= ~(kj|bit j)
// — zero ballots / exec juggling per selection. Selections recorded batched
// after the chain via rank = popcount(selw & below). supp is u64/word.
// readlane returns int — cast through unsigned before widening to u64.
#define DECLW(s) u64 kw##s; unsigned cw##s; uint4 p0##s, p1##s;
#define LOADW(s, wexp) { int w_ = (wexp); int c_ = 64 * w_ + lane; \
  kw##s = diagb[(size_t)w_ * 64 + lane]; cw##s = rcb[c_]; \
  const uint4* rp_ = (const uint4*)(rtb + (size_t)c_ * L); p0##s = rp_[0]; p1##s = rp_[1]; }
#define PROCW(s, wexp) { int w_ = (wexp); \
  if (w_ < nw && sc < POST) { \
    const int base_ = 64 * w_; const int myc_ = base_ + lane; \
    const u64 suppw_ = supp[w_]; \
    const bool alv_ = (myc_ < n) && !((suppw_ >> lane) & 1ull); \
    u64 act_ = __ballot(alv_); \
    u64 selw_ = 0ull; \
    const int scb_ = sc; \
    const unsigned klo_ = (unsigned)kw##s, khi_ = (unsigned)(kw##s >> 32); \
    while (act_ && sc < POST) { \
      const int j_ = (int)__builtin_ctzll(act_); \
      const u64 kj_ = ((u64)(unsigned)__builtin_amdgcn_readlane((int)khi_, j_) << 32) | \
                      (u64)(unsigned)__builtin_amdgcn_readlane((int)klo_, j_); \
      selw_ |= 1ull << j_; sc++; \
      act_ &= ~(kj_ | (1ull << j_)); } \
    const bool selme_ = ((selw_ >> lane) & 1ull) != 0ull; \
    if (selme_) { \
      const int rank_ = scb_ + (int)__popcll(selw_ & ((1ull << lane) - 1ull)); \
      sel[rank_] = myc_; \
      const int ce_ = min((int)cw##s, L); \
      uint4 p2_ = {0,0,0,0}, p3_ = {0,0,0,0}; \
      if (ce_ > 16) { \
        const uint4* rp_ = (const uint4*)(rtb + (size_t)myc_ * L); \
        p2_ = rp_[2]; p3_ = rp_[3]; \
      } \
      unsigned ev_[8] = {p0##s.x, p0##s.y, p0##s.z, p0##s.w, p1##s.x, p1##s.y, p1##s.z, p1##s.w}; \
      _Pragma("unroll") \
      for (int u_ = 0; u_ < 8; ++u_) { \
        if (2 * u_ < ce_)     { int t_ = (int)(ev_[u_] & 0xffffu); atomicOr(&supp[t_ >> 6], 1ull << (t_ & 63)); } \
        if (2 * u_ + 1 < ce_) { int t_ = (int)(ev_[u_] >> 16);     atomicOr(&supp[t_ >> 6], 1ull << (t_ & 63)); } } \
      if (ce_ > 16) { \
        unsigned e2_[8] = {p2_.x, p2_.y, p2_.z, p2_.w, p3_.x, p3_.y, p3_.z, p3_.w}; \
        _Pragma("unroll") \
        for (int u_ = 0; u_ < 8; ++u_) { \
          if (16 + 2 * u_ < ce_)     { int t_ = (int)(e2_[u_] & 0xffffu); atomicOr(&supp[t_ >> 6], 1ull << (t_ & 63)); } \
          if (16 + 2 * u_ + 1 < ce_) { int t_ = (int)(e2_[u_] >> 16);     atomicOr(&supp[t_ >> 6], 1ull << (t_ & 63)); } } } } \
    u64 om_ = __ballot(selme_ && ((int)cw##s > L)); \
    while (om_) { \
      int j_ = (int)__builtin_ctzll(om_); om_ &= om_ - 1; \
      const int mc_ = base_ + j_; \
      float ax1_ = CX1[mc_], ay1_ = CY1[mc_], ax2_ = CX2[mc_], ay2_ = CY2[mc_], aar_ = CAR[mc_]; \
      for (int c2_ = base_ + 64 + lane; c2_ < n; c2_ += 64) { \
        float ovr_ = iou_ref(ax1_, ay1_, ax2_, ay2_, aar_, CX1[c2_], CY1[c2_], CX2[c2_], CY2[c2_], CAR[c2_]); \
        if (ovr_ > NMS_T) atomicOr(&supp[c2_ >> 6], 1ull << (c2_ & 63)); } } } }

__global__ __launch_bounds__(64) void scan_kernel(
    const float* __restrict__ cx1, const float* __restrict__ cy1,
    const float* __restrict__ cx2, const float* __restrict__ cy2,
    const float* __restrict__ car, const int* __restrict__ ncand,
    const u64* __restrict__ diagT, const unsigned* __restrict__ rowcnt,
    const unsigned short* __restrict__ rows_t, int L,
    float* __restrict__ out) {
  const int b = blockIdx.x;
  const int lane = threadIdx.x;
  __shared__ u64 supp[WPB];
  __shared__ int sel[POST];
  for (int idx = lane; idx < WPB; idx += 64) supp[idx] = 0ull;

  const int n = ncand[b];
  const u64* diagb = diagT + (size_t)b * WPB * 64;
  const unsigned* rcb = rowcnt + (size_t)b * CPAD;
  const unsigned short* rtb = rows_t + (size_t)b * L * CPAD;
  const float* CX1 = cx1 + (size_t)b * CPAD;
  const float* CY1 = cy1 + (size_t)b * CPAD;
  const float* CX2 = cx2 + (size_t)b * CPAD;
  const float* CY2 = cy2 + (size_t)b * CPAD;
  const float* CAR = car + (size_t)b * CPAD;

  const int nw = (n + 63) >> 6;
  int sc = 0;

  DECLW(a0) DECLW(a1) DECLW(a2) DECLW(a3)
  DECLW(b0) DECLW(b1) DECLW(b2) DECLW(b3)

  if (nw > 0) {
    LOADW(a0, 0)
    LOADW(a1, min(1, WPB - 1))
    LOADW(a2, min(2, WPB - 1))
    LOADW(a3, min(3, WPB - 1))
    const int ng = (nw + 3) >> 2;
    for (int g = 0; g < ng && sc < POST; ++g) {
      const int wn = 4 * g + 4;
      LOADW(b0, min(wn + 0, WPB - 1))
      LOADW(b1, min(wn + 1, WPB - 1))
      LOADW(b2, min(wn + 2, WPB - 1))
      LOADW(b3, min(wn + 3, WPB - 1))
      PROCW(a0, 4 * g + 0)
      PROCW(a1, 4 * g + 1)
      PROCW(a2, 4 * g + 2)
      PROCW(a3, 4 * g + 3)
      kwa0 = kwb0; cwa0 = cwb0; p0a0 = p0b0; p1a0 = p1b0;
      kwa1 = kwb1; cwa1 = cwb1; p0a1 = p0b1; p1a1 = p1b1;
      kwa2 = kwb2; cwa2 = cwb2; p0a2 = p0b2; p1a2 = p1b2;
      kwa3 = kwb3; cwa3 = cwb3; p0a3 = p0b3; p1a3 = p1b3;
    }
  }

  float* roib = out + (size_t)b * POST * 4;
  float* maskb = out + (size_t)BATCH * POST * 4 + (size_t)b * POST;
  for (int t = lane; t < POST; t += 64) {
    if (t < sc) {
      int j = sel[t];
      float4 v = make_float4(CX1[j], CY1[j], CX2[j], CY2[j]);
      *(float4*)(roib + (size_t)t * 4) = v;
      maskb[t] = 1.0f;
    } else {
      *(float4*)(roib + (size_t)t * 4) = make_float4(0.f, 0.f, 0.f, 0.f);
      maskb[t] = 0.0f;
    }
  }
}

// ---------------- Fallback path (tiny-ws only) ----------------
__global__ __launch_bounds__(256) void decode_fb_kernel(
    const float* __restrict__ anchors, const float* __restrict__ cls,
    const float* __restrict__ bbox,
    float* __restrict__ bx1, float* __restrict__ by1,
    float* __restrict__ bx2, float* __restrict__ by2,
    unsigned* __restrict__ keys) {
  int i = blockIdx.x * 256 + threadIdx.x;
  if (i >= N_ANCHN) return;
  int b = blockIdx.y;
  float x1, y1, x2, y2; unsigned k;
  decode_one(anchors, cls, bbox, b, i, x1, y1, x2, y2, k);
  size_t o = (size_t)b * NPAD + i;
  bx1[o] = x1; by1[o] = y1; bx2[o] = x2; by2[o] = y2;
  keys[o] = k;
}

__global__ __launch_bounds__(1024) void prep_kernel(
    const unsigned* __restrict__ keys,
    const float* __restrict__ bx1, const float* __restrict__ by1,
    const float* __restrict__ bx2, const float* __restrict__ by2,
    unsigned char* __restrict__ flags,
    float* __restrict__ cx1, float* __restrict__ cy1,
    float* __restrict__ cx2, float* __restrict__ cy2,
    float* __restrict__ car, int* __restrict__ ncand) {
  const int b = blockIdx.x;
  const int tid = threadIdx.x;
  __shared__ unsigned hist[256];
  __shared__ unsigned ssc[1024];
  __shared__ unsigned sh_prefix, sh_k;
  const unsigned* kb = keys + (size_t)b * NPAD;

  if (tid == 0) { sh_prefix = 0u; sh_k = PRE; }
  __syncthreads();

  for (int level = 0; level < 4; ++level) {
    const int shift = 24 - 8 * level;
    if (tid < 256) hist[tid] = 0u;
    __syncthreads();
    unsigned pre = sh_prefix;
    for (int i = tid; i < N_ANCHN; i += 1024) {
      unsigned k = kb[i];
      bool match = (level == 0) || ((k >> (shift + 8)) == (pre >> (shift + 8)));
      if (match) atomicAdd(&hist[(k >> shift) & 255u], 1u);
    }
    __syncthreads();
    if (tid == 0) {
      unsigned kk = sh_k, cum = 0;
      for (int d = 255; d >= 0; --d) {
        unsigned c = hist[d];
        if (cum + c >= kk) { sh_k = kk - cum; sh_prefix = pre | ((unsigned)d << shift); break; }
        cum += c;
      }
    }
    __syncthreads();
  }
  const unsigned T = sh_prefix;

  unsigned local = 0;
  for (int i = tid; i < N_ANCHN; i += 1024) local += (kb[i] > T) ? 1u : 0u;
  ssc[tid] = local;
  __syncthreads();
  for (int off = 512; off > 0; off >>= 1) {
    if (tid < off) ssc[tid] += ssc[tid + off];
    __syncthreads();
  }
  const unsigned slots = PRE - ssc[0];
  __syncthreads();

  const int SEG = (N_ANCHN + 1023) / 1024;
  const float* X1 = bx1 + (size_t)b * NPAD;
  const float* Y1 = by1 + (size_t)b * NPAD;
  const float* X2 = bx2 + (size_t)b * NPAD;
  const float* Y2 = by2 + (size_t)b * NPAD;
  unsigned char* fb = flags + (size_t)b * NPAD;

  {
    int i0 = tid * SEG, i1 = min(N_ANCHN, i0 + SEG);
    unsigned cnt = 0;
    for (int i = i0; i < i1; ++i) cnt += (kb[i] == T) ? 1u : 0u;
    ssc[tid] = cnt;
    __syncthreads();
    for (int off = 1; off < 1024; off <<= 1) {
      unsigned v = (tid >= off) ? ssc[tid - off] : 0u;
      __syncthreads();
      ssc[tid] += v;
      __syncthreads();
    }
    unsigned r = ssc[tid] - cnt;
    for (int i = i0; i < i1; ++i) {
      unsigned k = kb[i];
      bool valid = (__fsub_rn(Y2[i], Y1[i]) >= MINSZ) && (__fsub_rn(X2[i], X1[i]) >= MINSZ);
      bool tie = (k == T);
      bool cand = valid && ((k > T) || (tie && r < slots));
      if (tie) r++;
      fb[i] = cand ? (unsigned char)1 : (unsigned char)0;
    }
  }
  __syncthreads();

  {
    int j0 = tid * SEG, j1 = min(N_ANCHN, j0 + SEG);
    unsigned cnt = 0;
    for (int j = j0; j < j1; ++j) cnt += fb[N_ANCHN - 1 - j];
    ssc[tid] = cnt;
    __syncthreads();
    for (int off = 1; off < 1024; off <<= 1) {
      unsigned v = (tid >= off) ? ssc[tid - off] : 0u;
      __syncthreads();
      ssc[tid] += v;
      __syncthreads();
    }
    unsigned p = ssc[tid] - cnt;
    if (tid == 0) ncand[b] = (int)ssc[1023];
    float* CX1 = cx1 + (size_t)b * CPAD;
    float* CY1 = cy1 + (size_t)b * CPAD;
    float* CX2 = cx2 + (size_t)b * CPAD;
    float* CY2 = cy2 + (size_t)b * CPAD;
    float* CAR = car + (size_t)b * CPAD;
    for (int j = j0; j < j1; ++j) {
      int i = N_ANCHN - 1 - j;
      if (fb[i]) {
        float x1v = X1[i], y1v = Y1[i], x2v = X2[i], y2v = Y2[i];
        CX1[p] = x1v; CY1[p] = y1v; CX2[p] = x2v; CY2[p] = y2v;
        CAR[p] = __fmul_rn(__fadd_rn(__fsub_rn(x2v, x1v), 1.0f),
                           __fadd_rn(__fsub_rn(y2v, y1v), 1.0f));
        p++;
      }
    }
  }
}

__global__ __launch_bounds__(1024) void nms_kernel(
    const float* __restrict__ cx1, const float* __restrict__ cy1,
    const float* __restrict__ cx2, const float* __restrict__ cy2,
    const float* __restrict__ car, const int* __restrict__ ncand,
    float* __restrict__ out) {
  const int b = blockIdx.x;
  const int tid = threadIdx.x;
  __shared__ float sx1[POST], sy1[POST], sx2[POST], sy2[POST], sar[POST];
  __shared__ int Lbuf[1024];
  __shared__ int wcount[16];
  __shared__ int sh_sc;

  const float* CX1 = cx1 + (size_t)b * CPAD;
  const float* CY1 = cy1 + (size_t)b * CPAD;
  const float* CX2 = cx2 + (size_t)b * CPAD;
  const float* CY2 = cy2 + (size_t)b * CPAD;
  const float* CAR = car + (size_t)b * CPAD;
  float* roib = out + (size_t)b * POST * 4;
  float* maskb = out + (size_t)BATCH * POST * 4 + (size_t)b * POST;

  const int n = ncand[b];
  if (tid == 0) sh_sc = 0;
  __syncthreads();
  const int lane = tid & 63;
  const int w = tid >> 6;

  for (int base = 0; base < n; base += 1024) {
    const int c = base + tid;
    bool pass = (c < n);
    float px1 = 0, py1 = 0, px2 = 0, py2 = 0, par = 0;
    if (pass) { px1 = CX1[c]; py1 = CY1[c]; px2 = CX2[c]; py2 = CY2[c]; par = CAR[c]; }
    const int sc0 = sh_sc;

    if (pass) {
      for (int k = 0; k < sc0; ++k) {
        float ovr = iou_ref(sx1[k], sy1[k], sx2[k], sy2[k], sar[k], px1, py1, px2, py2, par);
        if (ovr > NMS_T) { pass = false; break; }
      }
    }

    unsigned long long bal = __ballot(pass);
    if (lane == 0) wcount[w] = (int)__popcll(bal);
    __syncthreads();
    int off = 0;
    for (int q = 0; q < 16; ++q) off += (q < w) ? wcount[q] : 0;
    if (pass) Lbuf[off + (int)__popcll(bal & ((1ULL << lane) - 1ULL))] = c;
    __syncthreads();

    if (tid < 64) {
      int total = 0;
      for (int q = 0; q < 16; ++q) total += wcount[q];
      int sc = sc0;
      for (int g = 0; g < total && sc < POST; g += 64) {
        int idx = (g + lane < total) ? Lbuf[g + lane] : -1;
        float qx1 = 0, qy1 = 0, qx2 = 0, qy2 = 0, qar = 0;
        bool al = (idx >= 0);
        if (al) { qx1 = CX1[idx]; qy1 = CY1[idx]; qx2 = CX2[idx]; qy2 = CY2[idx]; qar = CAR[idx]; }
        for (int k = sc0; k < sc && al; ++k) {
          float ovr = iou_ref(sx1[k], sy1[k], sx2[k], sy2[k], sar[k], qx1, qy1, qx2, qy2, qar);
          if (ovr > NMS_T) al = false;
        }
        unsigned long long alive = __ballot(al);
        while (alive && sc < POST) {
          int j = (int)__builtin_ctzll(alive);
          float jx1 = __shfl(qx1, j), jy1 = __shfl(qy1, j);
          float jx2 = __shfl(qx2, j), jy2 = __shfl(qy2, j), jar = __shfl(qar, j);
          float ovr = iou_ref(jx1, jy1, jx2, jy2, jar, qx1, qy1, qx2, qy2, qar);
          unsigned long long killm = __ballot(ovr > NMS_T);
          alive &= ~killm;
          alive &= ~(1ULL << j);
          if (lane == 0) {
            sx1[sc] = jx1; sy1[sc] = jy1; sx2[sc] = jx2; sy2[sc] = jy2; sar[sc] = jar;
            roib[(size_t)sc * 4 + 0] = jx1;
            roib[(size_t)sc * 4 + 1] = jy1;
            roib[(size_t)sc * 4 + 2] = jx2;
            roib[(size_t)sc * 4 + 3] = jy2;
          }
          sc++;
        }
      }
      if (lane == 0) sh_sc = sc;
    }
    __syncthreads();
    if (sh_sc >= POST) break;
  }
  __syncthreads();

  const int sc = sh_sc;
  for (int t = tid; t < POST; t += 1024) {
    if (t >= sc) {
      roib[(size_t)t * 4 + 0] = 0.f; roib[(size_t)t * 4 + 1] = 0.f;
      roib[(size_t)t * 4 + 2] = 0.f; roib[(size_t)t * 4 + 3] = 0.f;
    }
    maskb[t] = (t < sc) ? 1.0f : 0.0f;
  }
}

extern "C" void kernel_launch(void* const* d_in, const int* in_sizes, int n_in,
                              void* d_out, int out_size, void* d_ws, size_t ws_size,
                              hipStream_t stream) {
  const float* anchors = (const float*)d_in[0];
  const float* cls = (const float*)d_in[1];
  const float* bbox = (const float*)d_in[2];
  float* out = (float*)d_out;
  char* ws = (char*)d_ws;

  // ---- persistent region ----
  size_t o = 0;
  float* cx1 = (float*)(ws + o); o += (size_t)BATCH * CPAD * 4;
  float* cy1 = (float*)(ws + o); o += (size_t)BATCH * CPAD * 4;
  float* cx2 = (float*)(ws + o); o += (size_t)BATCH * CPAD * 4;
  float* cy2 = (float*)(ws + o); o += (size_t)BATCH * CPAD * 4;
  float* car = (float*)(ws + o); o += (size_t)BATCH * CPAD * 4;
  int* ncand = (int*)(ws + o); o += 256;
  u64* diag = (u64*)(ws + o); o += (size_t)BATCH * WPB * 64 * 8;
  unsigned* rowcnt = (unsigned*)(ws + o); o += (size_t)BATCH * CPAD * 4;
  float* wminx1 = (float*)(ws + o); o += (size_t)BATCH * WPB * 4;
  float* wmaxx2 = (float*)(ws + o); o += (size_t)BATCH * WPB * 4;
  float* sx1 = (float*)(ws + o); o += (size_t)BATCH * CPAD * 4;
  float* sy1 = (float*)(ws + o); o += (size_t)BATCH * CPAD * 4;
  float* sx2 = (float*)(ws + o); o += (size_t)BATCH * CPAD * 4;
  float* sy2 = (float*)(ws + o); o += (size_t)BATCH * CPAD * 4;
  float* sar = (float*)(ws + o); o += (size_t)BATCH * CPAD * 4;
  int* sperm = (int*)(ws + o); o += (size_t)BATCH * CPAD * 4;
  size_t overlay = o;     // decode region and rows_t share this space
  unsigned* keys = (unsigned*)(ws + overlay);
  float* bx1 = (float*)(ws + overlay + (size_t)BATCH * NPAD * 4 * 1);
  float* by1 = (float*)(ws + overlay + (size_t)BATCH * NPAD * 4 * 2);
  float* bx2 = (float*)(ws + overlay + (size_t)BATCH * NPAD * 4 * 3);
  float* by2 = (float*)(ws + overlay + (size_t)BATCH * NPAD * 4 * 4);
  size_t decode_bytes = (size_t)BATCH * NPAD * 4 * 5;
  unsigned short* rows_t = (unsigned short*)(ws + overlay);  // build writes AFTER prepsort reads

  int L = 0;
  for (int Ltry = 32; Ltry >= 16; Ltry -= 16) {
    size_t rows_bytes = (size_t)BATCH * Ltry * CPAD * 2;
    size_t need = overlay + (decode_bytes > rows_bytes ? decode_bytes : rows_bytes);
    if (ws_size >= need) { L = Ltry; break; }
  }

  if (L > 0) {
    dim3 dgrid((N_ANCHN + 255) / 256 + 1, BATCH);   // last x-block zeroes diag/rowcnt
    decode_kernel<<<dgrid, 256, 0, stream>>>(anchors, cls, bbox, bx1, by1, bx2, by2,
                                             keys, diag, rowcnt);
    prepsort_kernel<<<BATCH, 1024, 0, stream>>>(keys, bx1, by1, bx2, by2,
                                                cx1, cy1, cx2, cy2, car, ncand,
                                                sx1, sy1, sx2, sy2, sar, sperm,
                                                wminx1, wmaxx2);
    build_kernel<<<dim3(WPB, (WPB + 15) / 16, BATCH), 256, 0, stream>>>(
        sx1, sy1, sx2, sy2, sar, sperm, ncand, wminx1, wmaxx2,
        diag, rowcnt, rows_t, L);
    scan_kernel<<<BATCH, 64, 0, stream>>>(cx1, cy1, cx2, cy2, car, ncand,
                                          diag, rowcnt, rows_t, L, out);
  } else {
    // tiny-ws fallback: round-1 layout + kernels
    size_t f = 0;
    unsigned* fkeys = (unsigned*)(ws + f); f += (size_t)BATCH * NPAD * 4;
    float* fbx1 = (float*)(ws + f); f += (size_t)BATCH * NPAD * 4;
    float* fby1 = (float*)(ws + f); f += (size_t)BATCH * NPAD * 4;
    float* fbx2 = (float*)(ws + f); f += (size_t)BATCH * NPAD * 4;
    float* fby2 = (float*)(ws + f); f += (size_t)BATCH * NPAD * 4;
    float* fcx1 = (float*)(ws + f); f += (size_t)BATCH * CPAD * 4;
    float* fcy1 = (float*)(ws + f); f += (size_t)BATCH * CPAD * 4;
    float* fcx2 = (float*)(ws + f); f += (size_t)BATCH * CPAD * 4;
    float* fcy2 = (float*)(ws + f); f += (size_t)BATCH * CPAD * 4;
    float* fcar = (float*)(ws + f); f += (size_t)BATCH * CPAD * 4;
    unsigned char* fflags = (unsigned char*)(ws + f); f += (size_t)BATCH * NPAD;
    int* fncand = (int*)(ws + f); f += 256;

    dim3 dgrid((N_ANCHN + 255) / 256, BATCH);
    decode_fb_kernel<<<dgrid, 256, 0, stream>>>(anchors, cls, bbox, fbx1, fby1, fbx2, fby2, fkeys);
    prep_kernel<<<BATCH, 1024, 0, stream>>>(fkeys, fbx1, fby1, fbx2, fby2, fflags,
                                            fcx1, fcy1, fcx2, fcy2, fcar, fncand);
    nms_kernel<<<BATCH, 1024, 0, stream>>>(fcx1, fcy1, fcx2, fcy2, fcar, fncand, out);
  }
}